// Round 9
// baseline (3341.241 us; speedup 1.0000x reference)
//
#include <hip/hip_runtime.h>

#define T_   256
#define HID_ 1024
#define D2   512

typedef __attribute__((ext_vector_type(8))) short  short8;
typedef __attribute__((ext_vector_type(8))) __bf16 bf16x8;
typedef __attribute__((ext_vector_type(4))) float  f32x4;

__device__ __forceinline__ float sigmoidf_(float x) {
    return __fdividef(1.0f, 1.0f + __expf(-x));
}
__device__ __forceinline__ float tanhf_(float x) {
    return 1.0f - __fdividef(2.0f, 1.0f + __expf(2.0f * x));
}
__device__ __forceinline__ unsigned short bf16hi(float x) {
    unsigned u = __float_as_uint(x);
    return (unsigned short)((u + 0x7FFFu + ((u >> 16) & 1u)) >> 16);
}
__device__ __forceinline__ float bf2f(unsigned short h) {
    return __uint_as_float((unsigned)h << 16);
}
__device__ __forceinline__ f32x4 mfma_(short8 a, short8 b, f32x4 c) {
    union { short8 s; bf16x8 b; } ua, ub;
    ua.s = a; ub.s = b;
    return __builtin_amdgcn_mfma_f32_16x16x32_bf16(ua.b, ub.b, c, 0, 0, 0);
}

// ---- raw asm memory ops (64-bit VGPR address form: works for divergent ptrs)
__device__ __forceinline__ void gl16c(short8& d, const void* p) {
    asm volatile("global_load_dwordx4 %0, %1, off sc0 sc1" : "=v"(d) : "v"(p));
}
__device__ __forceinline__ void gs8c(void* p, unsigned long long v) {
    asm volatile("global_store_dwordx2 %0, %1, off sc0 sc1"
                 :: "v"(p), "v"(v) : "memory");
}
// async global->LDS DMA, 16B/lane; LDS dest = wave-uniform base + lane*16.
// Per-lane GLOBAL addresses carry the inverse swizzle (m201 pattern).
__device__ __forceinline__ void glds16(const void* g, void* l) {
    __builtin_amdgcn_global_load_lds(
        (const __attribute__((address_space(1))) unsigned int*)g,
        (__attribute__((address_space(3))) unsigned int*)l, 16, 0, 0);
}
#define WAITV0()  asm volatile("s_waitcnt vmcnt(0)" ::: "memory")
#define WAITVN6() asm volatile("s_waitcnt vmcnt(6)" ::: "memory")
// ties "materialize" the A-frag regs so MFMAs can't be hoisted above the wait
#define WAITV2_TIE(H, L)  asm volatile("s_waitcnt vmcnt(2)"  : "+v"(H), "+v"(L) :: "memory")
#define WAITV0_TIE(H, L)  asm volatile("s_waitcnt vmcnt(0)"  : "+v"(H), "+v"(L) :: "memory")
#define ABAR() asm volatile("s_waitcnt lgkmcnt(0)\n\ts_barrier" ::: "memory")

// ---------------- prelim: W2 = fc2_w @ fc1_w, b2 = fc2_w@fc1_b + fc2_b ----
__global__ __launch_bounds__(256) void k_w2(
    const float* __restrict__ fc2_w, const float* __restrict__ fc1_w,
    const float* __restrict__ fc1_b, const float* __restrict__ fc2_b,
    float* __restrict__ W2, float* __restrict__ b2)
{
    int idx = blockIdx.x * 256 + threadIdx.x;   // 0..65535
    int r = idx >> 6, c = idx & 63;
    float acc = 0.f;
    for (int k = 0; k < D2; ++k)
        acc += fc2_w[(size_t)r * D2 + k] * fc1_w[(size_t)k * 64 + c];
    W2[idx] = acc;
    if (c == 0) {
        float a = fc2_b[r];
        for (int k = 0; k < D2; ++k)
            a += fc2_w[(size_t)r * D2 + k] * fc1_b[k];
        b2[r] = a;
    }
}

// -------- prelim: Wc = w_ih @ W2 (bf16 split planes), bc = w_ih@b2 + b_ih --
__global__ __launch_bounds__(256) void k_wc(
    const float* __restrict__ w_ih, const float* __restrict__ W2,
    const float* __restrict__ b2, const float* __restrict__ b_ih,
    unsigned short* __restrict__ wc_hi, unsigned short* __restrict__ wc_lo,
    float* __restrict__ bc)
{
    int idx = blockIdx.x * 256 + threadIdx.x;   // 0..196607
    int r = idx >> 6, c = idx & 63;
    float acc = 0.f;
    for (int k = 0; k < HID_; ++k)
        acc += w_ih[(size_t)r * HID_ + k] * W2[(size_t)k * 64 + c];
    unsigned short h = bf16hi(acc);
    wc_hi[idx] = h;
    wc_lo[idx] = bf16hi(acc - bf2f(h));
    if (c == 0) {
        float a = b_ih[r];
        for (int k = 0; k < HID_; ++k)
            a += w_ih[(size_t)r * HID_ + k] * b2[k];
        bc[r] = a;
    }
}

// ---------------- prelim: split w_hh into bf16 hi/lo planes ----------------
__global__ __launch_bounds__(256) void k_splitw(
    const float* __restrict__ w, unsigned short* __restrict__ hi,
    unsigned short* __restrict__ lo)
{
    int i4 = (blockIdx.x * 256 + threadIdx.x) * 4;
    float4 v = *(const float4*)(w + i4);
    float vv[4] = {v.x, v.y, v.z, v.w};
    unsigned short h4[4], l4[4];
    #pragma unroll
    for (int i = 0; i < 4; ++i) {
        h4[i] = bf16hi(vv[i]);
        l4[i] = bf16hi(vv[i] - bf2f(h4[i]));
    }
    *(unsigned long long*)(hi + i4) =
        (unsigned long long)h4[0] | ((unsigned long long)h4[1] << 16) |
        ((unsigned long long)h4[2] << 32) | ((unsigned long long)h4[3] << 48);
    *(unsigned long long*)(lo + i4) =
        (unsigned long long)l4[0] | ((unsigned long long)l4[1] << 16) |
        ((unsigned long long)l4[2] << 32) | ((unsigned long long)l4[3] << 48);
}

// ------- prelim: h0 -> bf16 split planes in fragment-granule layout --------
// layout: byte = (k>>5)*16384 + b*64 + ((k>>3)&3)*16 + (k&7)*2
__global__ __launch_bounds__(256) void k_split_h0(
    const float* __restrict__ hn, unsigned short* __restrict__ hi,
    unsigned short* __restrict__ lo)
{
    int gid = blockIdx.x * 256 + threadIdx.x;      // 0..32767
    int b = gid >> 7, kseg = gid & 127;
    const float* src = hn + (size_t)b * HID_ + kseg * 8;
    short8 h8, l8;
    #pragma unroll
    for (int i = 0; i < 8; ++i) {
        float v = src[i];
        unsigned short h = bf16hi(v);
        ((short*)&h8)[i] = (short)h;
        ((short*)&l8)[i] = (short)bf16hi(v - bf2f(h));
    }
    size_t off = (size_t)(kseg >> 2) * 8192 + b * 32 + (kseg & 3) * 8; // ushorts
    *(short8*)(hi + off) = h8;
    *(short8*)(lo + off) = l8;
}

// ---------------- main persistent GRU kernel (MFMA split-bf16) -------------
// R8 change (on the R5/R7 skeleton, K=64 granules, 15 intra-step ABARs):
// weight staging converted from {gl16->VGPR->ds_write} to DIRECT
// global_load_lds DMA (16B/lane). LDS dest is linear (span*1024B + lane*16);
// the per-lane GLOBAL addresses carry the inverse of the R4 XOR swizzle, so
// LDS contents are BYTE-IDENTICAL to R5's -> readers unchanged -> bitwise-
// identical output. Eliminates ~96 ds_write_b128/wave/step (~1/3 of all LDS
// instructions) + the bp weight registers + the wait->write serialization.
// Span decode (per chunk, 12 spans of 1024B): LDS short off = s12*512+l*8
//   -> row = s12*16 + (l>>2), q = l&3, seg = q ^ ((row>>1)&3),
//      plane = row/96, n = row%96  -> global frag addr (same as old writer).
// vmcnt ledger (per wave; A = 2 sc0sc1 loads/granule, W = 6 lds-DMA):
//   pre-spin: x(2) gi_lds(6) W1_lds(6); vmcnt(6) forces x+gi; ABAR; gi-comp.
//   post-spin ABAR; W0_lds(6), A0(2), A1(2); vmcnt(2) forces W1,W0,A0; ABAR.
//   iter G: [G in 1..14: vmcnt(2) forces {A(G),W(G+1)}; ABAR]
//           [G<=13: issue W(G+2)_lds -> buf (G+2)%3 (safe: post-ABAR all
//            waves done reading it at compute G-1), issue A(G+2)]
//           compute G.  G=15: vmcnt(0).  A flies 2 intervals (L3 covered).
__global__ __launch_bounds__(256, 1) void k_gru(
    const float* __restrict__ input,
    const float* __restrict__ hn,
    const float* __restrict__ b_hh,
    const float* __restrict__ bc,
    const unsigned short* __restrict__ whh_hi,
    const unsigned short* __restrict__ whh_lo,
    const unsigned short* __restrict__ wc_hi,
    const unsigned short* __restrict__ wc_lo,
    unsigned short* __restrict__ hxA_hi, unsigned short* __restrict__ hxA_lo,
    unsigned short* __restrict__ hxB_hi, unsigned short* __restrict__ hxB_lo,
    float* __restrict__ hn_out,
    int* __restrict__ bar)
{
    const int g = blockIdx.x, ct = g & 31, bt = g >> 5;
    const int j0 = ct << 5, b0 = bt << 5;
    const int tid = threadIdx.x, lane = tid & 63, wid = tid >> 6;
    const int mh = wid & 1, kh = wid >> 1;
    const int l15 = lane & 15, quad = lane >> 4;

    __shared__ short smB[36864];              // 3 ring bufs x 12288 shorts
    float* smF = (float*)smB;                 // C-dump alias (post-K-loop)
    const int SIN_ = 4672, SHN_ = 6784;

    // ---- staging descriptors: 6 DMA spans per wave per K64 granule ----
    // span js = wid*6 + jj covers LDS [js*1024, js*1024+1024) of a granule
    // buffer; lane l fetches the fragment the swizzled readers expect there.
    const char* wsp[6];   // per-lane w_hh source (granule 0)
    const char* csp[6];   // per-lane Wc source
    int ldsp[6];          // wave-uniform LDS short offset within a buffer
    #pragma unroll
    for (int jj = 0; jj < 6; ++jj) {
        int js  = wid * 6 + jj;          // 0..23
        int cg  = js / 12;               // chunk within granule
        int s12 = js % 12;               // 1KB span within chunk
        int rowg = s12 * 16 + (lane >> 2);
        int q   = lane & 3;
        int ss  = q ^ ((rowg >> 1) & 3); // inverse of the R4 XOR swizzle
        int pln = rowg / 96, n = rowg % 96;
        int grow = (n >> 5) * HID_ + j0 + (n & 31);
        wsp[jj] = (const char*)(pln ? whh_lo : whh_hi)
                + (size_t)grow * 2048u + (size_t)(ss * 16 + cg * 64);
        csp[jj] = (const char*)(pln ? wc_lo : wc_hi)
                + (size_t)grow * 128u + (size_t)(ss * 16 + cg * 64);
        ldsp[jj] = __builtin_amdgcn_readfirstlane(js * 512);
    }
    const int foff = l15 * 32 + ((quad * 8) ^ (((l15 >> 1) & 3) << 3));   // swz
    const size_t aoff = (size_t)((b0 + mh * 16 + l15) * 64 + quad * 16);
    const char* aAh = (const char*)hxA_hi + aoff;
    const char* aAl = (const char*)hxA_lo + aoff;
    const char* aBh = (const char*)hxB_hi + aoff;
    const char* aBl = (const char*)hxB_lo + aoff;
    const float* xrow = input + (size_t)(b0 + mh * 16 + l15) * (T_ * 64)
                              + kh * 32 + quad * 8;

    // ---- gate-phase statics: thread owns (b = b0+gb, j = j0+gj4..+3) -----
    const int gb = tid >> 3, gj4 = (tid & 7) << 2;
    float hreg[4], br[4], bz[4], bni[4], bnh[4];
    #pragma unroll
    for (int i = 0; i < 4; ++i) {
        int j = j0 + gj4 + i;
        hreg[i] = hn[(size_t)(b0 + gb) * HID_ + j];
        br[i]  = bc[j] + b_hh[j];
        bz[i]  = bc[1024 + j] + b_hh[1024 + j];
        bni[i] = bc[2048 + j];
        bnh[i] = b_hh[2048 + j];
    }
    const size_t hoff = (size_t)(ct * 16384 + (b0 + gb) * 64 + gj4 * 2);
    char* sAh = (char*)hxA_hi + hoff; char* sAl = (char*)hxA_lo + hoff;
    char* sBh = (char*)hxB_hi + hoff; char* sBl = (char*)hxB_lo + hoff;
    const int g73 = gb * 73, g33 = gb * 33;

    int* flags = bar + bt * 128;   // 32 per-producer flags, 128B (coalesced)

    short8 ab[3][2];   // A-frag banks [granule%3][hi/lo]
    f32x4 acc[6], acci[2];

#define ISSUE_WLDS(BUF, GG)                                                   \
  { _Pragma("unroll")                                                         \
    for (int jj_ = 0; jj_ < 6; ++jj_)                                         \
        glds16(wsp[jj_] + (size_t)(GG) * 128u,                                \
               (short*)smB + (BUF) * 12288 + ldsp[jj_]); }
#define GH_CHUNK(RB, AH, AL)                                                  \
  { _Pragma("unroll")                                                         \
    for (int nt = 0; nt < 6; ++nt) {                                          \
        short8 bh_ = *(const short8*)(smB + (RB) + nt * 512 + foff);          \
        short8 bl_ = *(const short8*)(smB + (RB) + 3072 + nt * 512 + foff);   \
        f32x4 v_ = mfma_(AH, bh_, acc[nt]);                                   \
        v_ = mfma_(AH, bl_, v_);                                              \
        v_ = mfma_(AL, bh_, v_);                                              \
        acc[nt] = v_; } }

    #pragma unroll 1
    for (int t = 0; t < 256; ++t) {
        const char* rh = (t & 1) ? aBh : aAh;   // read planes (h in)
        const char* rl = (t & 1) ? aBl : aAl;
        char* wh = (t & 1) ? sAh : sBh;         // write planes (h out)
        char* wl = (t & 1) ? sAl : sBl;

        // ---- x_t load + split; gi + W(1) staging via LDS-DMA ----
        float xv[8];
        *(float4*)&xv[0] = *(const float4*)(xrow + (size_t)t * 64);
        *(float4*)&xv[4] = *(const float4*)(xrow + (size_t)t * 64 + 4);
        short8 xa_hi, xa_lo;
        #pragma unroll
        for (int i = 0; i < 8; ++i) {
            unsigned short h = bf16hi(xv[i]);
            ((short*)&xa_hi)[i] = (short)h;
            ((short*)&xa_lo)[i] = (short)bf16hi(xv[i] - bf2f(h));
        }
        #pragma unroll
        for (int jj = 0; jj < 6; ++jj)          // gi (Wc, 2 chunks) -> buf0
            glds16(csp[jj], (short*)smB + ldsp[jj]);
        ISSUE_WLDS(1, 1);                       // w_hh granule 1 -> buf1
        WAITVN6();                              // force x+gi; W1 stays in flight
        ABAR();
        // ---- gi compute (Wc chunk = kh), inits accumulators ----
        {
            const int rb = kh * 6144;
            #pragma unroll
            for (int nt = 0; nt < 6; ++nt) {
                short8 bh_ = *(const short8*)(smB + rb + nt * 512 + foff);
                short8 bl_ = *(const short8*)(smB + rb + 3072 + nt * 512 + foff);
                f32x4 z = {0.f, 0.f, 0.f, 0.f};
                f32x4 v = mfma_(xa_hi, bh_, z);
                v = mfma_(xa_hi, bl_, v);
                v = mfma_(xa_lo, bh_, v);
                if (nt < 4) { acc[nt] = v; }
                else { acci[nt - 4] = v; acc[nt] = z; }
            }
        }
        // ---- wait for h(t): parallel poll of the 32 producer flags ----
        if (t > 0 && wid == 0) {
            int fl = (lane < 32)
                ? __hip_atomic_load(flags + lane, __ATOMIC_RELAXED,
                                    __HIP_MEMORY_SCOPE_SYSTEM)
                : t;
            while (__any(fl < t)) {
                __builtin_amdgcn_s_sleep(1);
                fl = (lane < 32)
                    ? __hip_atomic_load(flags + lane, __ATOMIC_RELAXED,
                                        __HIP_MEMORY_SCOPE_SYSTEM)
                    : t;
            }
        }
        ABAR();
        // ---- prologue: W0 -> buf0 (all gi reads done), A(0), A(1) ----
        ISSUE_WLDS(0, 0);
        gl16c(ab[0][0], rh + (size_t)kh * 16384);
        gl16c(ab[0][1], rl + (size_t)kh * 16384);
        gl16c(ab[1][0], rh + (size_t)(2 + kh) * 16384);
        gl16c(ab[1][1], rl + (size_t)(2 + kh) * 16384);
        WAITV2_TIE(ab[0][0], ab[0][1]);   // forces W1, W0, A0; leaves A1
        ABAR();
        // ---- gh pipeline: 16 K64 granules, ring-3, LDS-DMA prefetch ----
        #pragma unroll
        for (int G = 0; G < 16; ++G) {
            if (G >= 1 && G <= 14) {
                WAITV2_TIE(ab[G % 3][0], ab[G % 3][1]);  // {A(G), W(G+1)}
                ABAR();
            } else if (G == 15) {
                WAITV0_TIE(ab[0][0], ab[0][1]);          // A(15)
            }
            if (G <= 13) {
                ISSUE_WLDS((G + 2) % 3, G + 2);
                gl16c(ab[(G + 2) % 3][0], rh + (size_t)(2 * (G + 2) + kh) * 16384);
                gl16c(ab[(G + 2) % 3][1], rl + (size_t)(2 * (G + 2) + kh) * 16384);
            }
            GH_CHUNK((G % 3) * 12288 + kh * 6144, ab[G % 3][0], ab[G % 3][1]);
        }
        __syncthreads();
        // ---- dump C fragments (aliased over ring bufs) ----
        {
            const int row = mh * 16 + quad * 4;
            #pragma unroll
            for (int nt = 0; nt < 4; ++nt)
                #pragma unroll
                for (int r = 0; r < 4; ++r)
                    smF[kh * 2336 + (row + r) * 73 + nt * 16 + l15] = acc[nt][r];
            #pragma unroll
            for (int jn = 0; jn < 2; ++jn)
                #pragma unroll
                for (int r = 0; r < 4; ++r) {
                    smF[SHN_ + kh * 1056 + (row + r) * 33 + jn * 16 + l15] = acc[4 + jn][r];
                    smF[SIN_ + kh * 1056 + (row + r) * 33 + jn * 16 + l15] = acci[jn][r];
                }
        }
        __syncthreads();
        // ---- gate phase: thread owns (gb, gj4..+3); hprev in registers ----
        unsigned short ph4[4], pl4[4];
        #pragma unroll
        for (int i = 0; i < 4; ++i) {
            int cl = gj4 + i;
            float rp = smF[g73 + cl] + smF[2336 + g73 + cl] + br[i];
            float zp = smF[g73 + 32 + cl] + smF[2336 + g73 + 32 + cl] + bz[i];
            float ip = smF[SIN_ + g33 + cl] + smF[SIN_ + 1056 + g33 + cl] + bni[i];
            float hp = smF[SHN_ + g33 + cl] + smF[SHN_ + 1056 + g33 + cl] + bnh[i];
            float rr = sigmoidf_(rp);
            float zz = sigmoidf_(zp);
            float nn = tanhf_(ip + rr * hp);
            float hv = (1.0f - zz) * nn + zz * hreg[i];
            hreg[i] = hv;
            unsigned short hh = bf16hi(hv);
            ph4[i] = hh;
            pl4[i] = bf16hi(hv - bf2f(hh));
        }
        unsigned long long pk_hi =
            (unsigned long long)ph4[0] | ((unsigned long long)ph4[1] << 16) |
            ((unsigned long long)ph4[2] << 32) | ((unsigned long long)ph4[3] << 48);
        unsigned long long pk_lo =
            (unsigned long long)pl4[0] | ((unsigned long long)pl4[1] << 16) |
            ((unsigned long long)pl4[2] << 32) | ((unsigned long long)pl4[3] << 48);
        gs8c(wh, pk_hi);
        gs8c(wl, pk_lo);
        if (t == 255) {
            #pragma unroll
            for (int i = 0; i < 4; ++i)
                hn_out[(size_t)(b0 + gb) * HID_ + j0 + gj4 + i] = hreg[i];
        }
        WAITV0();           // h-plane stores at coherence point
        __syncthreads();    // whole block done
        if (t < 255 && tid == 0)
            __hip_atomic_store(flags + ct, t + 1, __ATOMIC_RELAXED,
                               __HIP_MEMORY_SCOPE_SYSTEM);
    }
#undef GH_CHUNK
#undef ISSUE_WLDS
}

// ---------------- fc3: out3 = relu(relu(h) @ fc3_wT + fc3_b) --------------
__global__ __launch_bounds__(256) void k_fc3(
    const float* __restrict__ h, const float* __restrict__ fc3_w,
    const float* __restrict__ fc3_b, float* __restrict__ out3)
{
    const int bt = blockIdx.x >> 3;
    const int dt = blockIdx.x & 7;
    const int b0 = bt << 6;
    const int d0 = dt << 6;
    const int tid = threadIdx.x;
    const int tx = tid & 15, ty = tid >> 4;

    __shared__ float sh_h[64][36];
    __shared__ float sh_w[64][36];

    float acc[4][4] = {};
    const int lr = tid >> 3;
    const int lc = (tid & 7) << 2;

    for (int kk = 0; kk < HID_; kk += 32) {
        #pragma unroll
        for (int p = 0; p < 2; ++p) {
            int row = lr + (p << 5);
            float4 v = *(const float4*)(h + (size_t)(b0 + row) * HID_ + kk + lc);
            v.x = fmaxf(v.x, 0.f); v.y = fmaxf(v.y, 0.f);
            v.z = fmaxf(v.z, 0.f); v.w = fmaxf(v.w, 0.f);
            *(float4*)&sh_h[row][lc] = v;
            *(float4*)&sh_w[row][lc] =
                *(const float4*)(fc3_w + (size_t)(d0 + row) * HID_ + kk + lc);
        }
        __syncthreads();
        #pragma unroll
        for (int k = 0; k < 32; ++k) {
            float hv[4], wv[4];
            #pragma unroll
            for (int i = 0; i < 4; ++i) hv[i] = sh_h[ty + (i << 4)][k];
            #pragma unroll
            for (int q = 0; q < 4; ++q) wv[q] = sh_w[tx + (q << 4)][k];
            #pragma unroll
            for (int i = 0; i < 4; ++i)
                #pragma unroll
                for (int q = 0; q < 4; ++q)
                    acc[i][q] += hv[i] * wv[q];
        }
        __syncthreads();
    }
    #pragma unroll
    for (int i = 0; i < 4; ++i) {
        int b = b0 + ty + (i << 4);
        #pragma unroll
        for (int q = 0; q < 4; ++q) {
            int d = d0 + tx + (q << 4);
            out3[(size_t)b * D2 + d] = fmaxf(acc[i][q] + fc3_b[d], 0.f);
        }
    }
}

// ---------------- heads: params[b,o] = out3[b,:]·heads_w[cid[b],o,:]+b ----
__global__ __launch_bounds__(256) void k_heads(
    const float* __restrict__ out3, const int* __restrict__ cult,
    const float* __restrict__ hw, const float* __restrict__ hb,
    float* __restrict__ params)
{
    int b = blockIdx.x;
    int o = threadIdx.x >> 4;
    int l = threadIdx.x & 15;
    int cid = cult[b];
    const float* w = hw + ((size_t)cid * 16 + o) * D2;
    const float* x = out3 + (size_t)b * D2;
    float acc = 0.f;
    #pragma unroll
    for (int m = 0; m < 8; ++m) {
        int d4 = (l + (m << 4)) << 2;
        float4 xv = *(const float4*)(x + d4);
        float4 wv = *(const float4*)(w + d4);
        acc += xv.x * wv.x + xv.y * wv.y + xv.z * wv.z + xv.w * wv.w;
    }
    #pragma unroll
    for (int s = 1; s < 16; s <<= 1)
        acc += __shfl_xor(acc, s, 16);
    if (l == 0)
        params[(size_t)b * 16 + o] = acc + hb[(size_t)cid * 16 + o];
}

extern "C" void kernel_launch(void* const* d_in, const int* in_sizes, int n_in,
                              void* d_out, int out_size, void* d_ws, size_t ws_size,
                              hipStream_t stream)
{
    const float* input = (const float*)d_in[0];
    const float* hn    = (const float*)d_in[1];
    const int*   cult  = (const int*)d_in[2];
    const float* fc1_w = (const float*)d_in[3];
    const float* fc1_b = (const float*)d_in[4];
    const float* fc2_w = (const float*)d_in[5];
    const float* fc2_b = (const float*)d_in[6];
    const float* w_ih  = (const float*)d_in[7];
    const float* w_hh  = (const float*)d_in[8];
    const float* b_ih  = (const float*)d_in[9];
    const float* b_hh  = (const float*)d_in[10];
    const float* fc3_w = (const float*)d_in[11];
    const float* fc3_b = (const float*)d_in[12];
    const float* hw    = (const float*)d_in[13];
    const float* hb    = (const float*)d_in[14];
    float* out = (float*)d_out;
    float* hn_out = out + 4096;          // params 256*16, then hn 256*1024

    char* ws = (char*)d_ws;
    int*   bar    = (int*)ws;                                   // 4 KB
    float* W2     = (float*)(ws + 4096);                        // 256 KB
    float* b2     = (float*)(ws + 266240);
    float* bc     = (float*)(ws + 270336);
    unsigned short* whh_hi = (unsigned short*)(ws + 282624);    // 6 MB
    unsigned short* whh_lo = (unsigned short*)(ws + 282624 + 6291456);
    unsigned short* wc_hi  = (unsigned short*)(ws + 12865536);
    unsigned short* wc_lo  = (unsigned short*)(ws + 13258752);
    unsigned short* hxA_hi = (unsigned short*)(ws + 13651968);
    unsigned short* hxA_lo = (unsigned short*)(ws + 14176256);
    unsigned short* hxB_hi = (unsigned short*)(ws + 14700544);
    unsigned short* hxB_lo = (unsigned short*)(ws + 15224832);
    float* out3   = (float*)(ws + 15749120);                    // 512 KB

    hipMemsetAsync(bar, 0, 4096, stream);
    k_w2<<<256, 256, 0, stream>>>(fc2_w, fc1_w, fc1_b, fc2_b, W2, b2);
    k_wc<<<768, 256, 0, stream>>>(w_ih, W2, b2, b_ih, wc_hi, wc_lo, bc);
    k_splitw<<<3072, 256, 0, stream>>>(w_hh, whh_hi, whh_lo);
    k_split_h0<<<128, 256, 0, stream>>>(hn, hxA_hi, hxA_lo);
    k_gru<<<256, 256, 0, stream>>>(input, hn, b_hh, bc,
                                   whh_hi, whh_lo, wc_hi, wc_lo,
                                   hxA_hi, hxA_lo, hxB_hi, hxB_lo,
                                   hn_out, bar);
    k_fc3<<<32, 256, 0, stream>>>(hn_out, fc3_w, fc3_b, out3);
    k_heads<<<256, 256, 0, stream>>>(out3, cult, hw, hb, out);
}

// Round 10
// 3129.426 us; speedup vs baseline: 1.0677x; 1.0677x over previous
//
#include <hip/hip_runtime.h>

#define T_   256
#define HID_ 1024
#define D2   512

typedef __attribute__((ext_vector_type(8))) short  short8;
typedef __attribute__((ext_vector_type(8))) __bf16 bf16x8;
typedef __attribute__((ext_vector_type(4))) float  f32x4;

__device__ __forceinline__ float sigmoidf_(float x) {
    return __fdividef(1.0f, 1.0f + __expf(-x));
}
__device__ __forceinline__ float tanhf_(float x) {
    return 1.0f - __fdividef(2.0f, 1.0f + __expf(2.0f * x));
}
__device__ __forceinline__ unsigned short bf16hi(float x) {
    unsigned u = __float_as_uint(x);
    return (unsigned short)((u + 0x7FFFu + ((u >> 16) & 1u)) >> 16);
}
__device__ __forceinline__ float bf2f(unsigned short h) {
    return __uint_as_float((unsigned)h << 16);
}
__device__ __forceinline__ f32x4 mfma_(short8 a, short8 b, f32x4 c) {
    union { short8 s; bf16x8 b; } ua, ub;
    ua.s = a; ub.s = b;
    return __builtin_amdgcn_mfma_f32_16x16x32_bf16(ua.b, ub.b, c, 0, 0, 0);
}

// ---- raw asm memory ops (64-bit VGPR address form: works for divergent ptrs)
__device__ __forceinline__ void gl16(short8& d, const void* p) {
    asm volatile("global_load_dwordx4 %0, %1, off" : "=v"(d) : "v"(p));
}
__device__ __forceinline__ void gl16c(short8& d, const void* p) {
    asm volatile("global_load_dwordx4 %0, %1, off sc0 sc1" : "=v"(d) : "v"(p));
}
// same, +1024B immediate (mh=1 batch half: 16 batches x 64B in the h-planes)
__device__ __forceinline__ void gl16c_o(short8& d, const void* p) {
    asm volatile("global_load_dwordx4 %0, %1, off offset:1024 sc0 sc1"
                 : "=v"(d) : "v"(p));
}
__device__ __forceinline__ void gs8c(void* p, unsigned long long v) {
    asm volatile("global_store_dwordx2 %0, %1, off sc0 sc1"
                 :: "v"(p), "v"(v) : "memory");
}
#define WAITV0()  asm volatile("s_waitcnt vmcnt(0)"  ::: "memory")
#define WAITV10() asm volatile("s_waitcnt vmcnt(10)" ::: "memory")
// ties "materialize" the A-frag regs so MFMAs can't be hoisted above the wait
#define WAITV14_T(A,B,C,D) asm volatile("s_waitcnt vmcnt(14)" \
    : "+v"(A), "+v"(B), "+v"(C), "+v"(D) :: "memory")
#define WAITV4_T(A,B,C,D)  asm volatile("s_waitcnt vmcnt(4)"  \
    : "+v"(A), "+v"(B), "+v"(C), "+v"(D) :: "memory")
#define WAITV0_T(A,B,C,D)  asm volatile("s_waitcnt vmcnt(0)"  \
    : "+v"(A), "+v"(B), "+v"(C), "+v"(D) :: "memory")
#define ABAR() asm volatile("s_waitcnt lgkmcnt(0)\n\ts_barrier" ::: "memory")

// ---------------- prelim: W2 = fc2_w @ fc1_w, b2 = fc2_w@fc1_b + fc2_b ----
__global__ __launch_bounds__(256) void k_w2(
    const float* __restrict__ fc2_w, const float* __restrict__ fc1_w,
    const float* __restrict__ fc1_b, const float* __restrict__ fc2_b,
    float* __restrict__ W2, float* __restrict__ b2)
{
    int idx = blockIdx.x * 256 + threadIdx.x;   // 0..65535
    int r = idx >> 6, c = idx & 63;
    float acc = 0.f;
    for (int k = 0; k < D2; ++k)
        acc += fc2_w[(size_t)r * D2 + k] * fc1_w[(size_t)k * 64 + c];
    W2[idx] = acc;
    if (c == 0) {
        float a = fc2_b[r];
        for (int k = 0; k < D2; ++k)
            a += fc2_w[(size_t)r * D2 + k] * fc1_b[k];
        b2[r] = a;
    }
}

// -------- prelim: Wc = w_ih @ W2 (bf16 split planes), bc = w_ih@b2 + b_ih --
__global__ __launch_bounds__(256) void k_wc(
    const float* __restrict__ w_ih, const float* __restrict__ W2,
    const float* __restrict__ b2, const float* __restrict__ b_ih,
    unsigned short* __restrict__ wc_hi, unsigned short* __restrict__ wc_lo,
    float* __restrict__ bc)
{
    int idx = blockIdx.x * 256 + threadIdx.x;   // 0..196607
    int r = idx >> 6, c = idx & 63;
    float acc = 0.f;
    for (int k = 0; k < HID_; ++k)
        acc += w_ih[(size_t)r * HID_ + k] * W2[(size_t)k * 64 + c];
    unsigned short h = bf16hi(acc);
    wc_hi[idx] = h;
    wc_lo[idx] = bf16hi(acc - bf2f(h));
    if (c == 0) {
        float a = b_ih[r];
        for (int k = 0; k < HID_; ++k)
            a += w_ih[(size_t)r * HID_ + k] * b2[k];
        bc[r] = a;
    }
}

// ---------------- prelim: split w_hh into bf16 hi/lo planes ----------------
__global__ __launch_bounds__(256) void k_splitw(
    const float* __restrict__ w, unsigned short* __restrict__ hi,
    unsigned short* __restrict__ lo)
{
    int i4 = (blockIdx.x * 256 + threadIdx.x) * 4;
    float4 v = *(const float4*)(w + i4);
    float vv[4] = {v.x, v.y, v.z, v.w};
    unsigned short h4[4], l4[4];
    #pragma unroll
    for (int i = 0; i < 4; ++i) {
        h4[i] = bf16hi(vv[i]);
        l4[i] = bf16hi(vv[i] - bf2f(h4[i]));
    }
    *(unsigned long long*)(hi + i4) =
        (unsigned long long)h4[0] | ((unsigned long long)h4[1] << 16) |
        ((unsigned long long)h4[2] << 32) | ((unsigned long long)h4[3] << 48);
    *(unsigned long long*)(lo + i4) =
        (unsigned long long)l4[0] | ((unsigned long long)l4[1] << 16) |
        ((unsigned long long)l4[2] << 32) | ((unsigned long long)l4[3] << 48);
}

// ------- prelim: h0 -> bf16 split planes in fragment-granule layout --------
// layout: byte = (k>>5)*16384 + b*64 + ((k>>3)&3)*16 + (k&7)*2
__global__ __launch_bounds__(256) void k_split_h0(
    const float* __restrict__ hn, unsigned short* __restrict__ hi,
    unsigned short* __restrict__ lo)
{
    int gid = blockIdx.x * 256 + threadIdx.x;      // 0..32767
    int b = gid >> 7, kseg = gid & 127;
    const float* src = hn + (size_t)b * HID_ + kseg * 8;
    short8 h8, l8;
    #pragma unroll
    for (int i = 0; i < 8; ++i) {
        float v = src[i];
        unsigned short h = bf16hi(v);
        ((short*)&h8)[i] = (short)h;
        ((short*)&l8)[i] = (short)bf16hi(v - bf2f(h));
    }
    size_t off = (size_t)(kseg >> 2) * 8192 + b * 32 + (kseg & 3) * 8; // ushorts
    *(short8*)(hi + off) = h8;
    *(short8*)(lo + off) = l8;
}

// ---------------- main persistent GRU kernel (MFMA split-bf16) -------------
// R9 (on the R7 skeleton; R8's LDS-DMA reverted — it regressed):
// wave remap (mh,kh) -> (ntg,kh). Each wave computes BOTH batch halves for
// HALF the nt tiles: ntg owns nt {2*ntg, 2*ntg+1, 4+ntg}. B fragments are
// now read from LDS ONCE per chunk (6 ds_read_b128/wave vs 12 — the two
// mh-waves previously read identical data), halving the per-interval LDS
// floor. A-loads double to 4/granule: mh=1 fetched via offset:1024 immediate
// on the same address (h-plane: 16 batches x 64B). Per-output accumulation
// chains are UNCHANGED (same chunk order per kh, same 3-mfma order, same
// gi init) -> bitwise-identical results; C-dump writes the same smF
// addresses with the same values (only the owning wave changed).
// vmcnt ledger (per wave; W=6 loads/granule, A=4/granule, in-order retire):
//   pre-spin: issue W0(6),W1(6)  [gi gp/x drained by WAITV0 before].
//   post-spin: A0(4); vmcnt(10) forces W0; write W0->buf0; A1(4); ABAR.
//   iter G<=13: issue W(G+2)(6) into bp[G&1], A(G+2)(4); vmcnt(14) forces
//     exactly {A(G), W(G+1)} (A flew 2 intervals -> L3 covered); write
//     W(G+1)->buf (G+1)%3; ABAR; compute chunk 2G+kh from buf G%3.
//   G=14: vmcnt(4) {A14,W15}; write W15->buf0; ABAR. G=15: vmcnt(0) {A15}.
__global__ __launch_bounds__(256, 1) void k_gru(
    const float* __restrict__ input,
    const float* __restrict__ hn,
    const float* __restrict__ b_hh,
    const float* __restrict__ bc,
    const unsigned short* __restrict__ whh_hi,
    const unsigned short* __restrict__ whh_lo,
    const unsigned short* __restrict__ wc_hi,
    const unsigned short* __restrict__ wc_lo,
    unsigned short* __restrict__ hxA_hi, unsigned short* __restrict__ hxA_lo,
    unsigned short* __restrict__ hxB_hi, unsigned short* __restrict__ hxB_lo,
    float* __restrict__ hn_out,
    int* __restrict__ bar)
{
    const int g = blockIdx.x, ct = g & 31, bt = g >> 5;
    const int j0 = ct << 5, b0 = bt << 5;
    const int tid = threadIdx.x, lane = tid & 63, wid = tid >> 6;
    const int ntg = wid & 1, kh = wid >> 1;
    const int l15 = lane & 15, quad = lane >> 4;

    __shared__ short smB[36864];              // 3 ring bufs x 12288 shorts
    float* smF = (float*)smB;                 // C-dump alias (post-K-loop)
    const int SIN_ = 4672, SHN_ = 6784;

    // ---- B staging descriptors: 3 x 16B segs per thread per K32 chunk ----
    const int t7 = tid & 127, pl = tid >> 7;
    const unsigned short* wsrc = pl ? whh_lo : whh_hi;
    const unsigned short* csrc = pl ? wc_lo : wc_hi;
    const char* wB[3]; const char* cB[3]; int lo_[3];
    #pragma unroll
    for (int i = 0; i < 3; ++i) {
        int sid = t7 + (i << 7);
        int n = sid >> 2, ss = sid & 3;
        int grow = (n >> 5) * HID_ + j0 + (n & 31);
        wB[i] = (const char*)wsrc + (size_t)grow * 2048u + (size_t)ss * 16u;
        cB[i] = (const char*)csrc + (size_t)grow * 128u + (size_t)ss * 16u;
        lo_[i] = (pl * 96 + n) * 32 + ((ss * 8) ^ (((n >> 1) & 3) << 3)); // swz
    }
    const int foff = l15 * 32 + ((quad * 8) ^ (((l15 >> 1) & 3) << 3));   // swz
    const size_t aoff = (size_t)((b0 + l15) * 64 + quad * 16);  // mh=0 base
    const char* aAh = (const char*)hxA_hi + aoff;
    const char* aAl = (const char*)hxA_lo + aoff;
    const char* aBh = (const char*)hxB_hi + aoff;
    const char* aBl = (const char*)hxB_lo + aoff;
    const float* xrow0 = input + (size_t)(b0 + l15) * (T_ * 64)
                               + kh * 32 + quad * 8;
    const float* xrow1 = xrow0 + (size_t)16 * (T_ * 64);

    // ---- gate-phase statics: thread owns (b = b0+gb, j = j0+gj4..+3) -----
    const int gb = tid >> 3, gj4 = (tid & 7) << 2;
    float hreg[4], br[4], bz[4], bni[4], bnh[4];
    #pragma unroll
    for (int i = 0; i < 4; ++i) {
        int j = j0 + gj4 + i;
        hreg[i] = hn[(size_t)(b0 + gb) * HID_ + j];
        br[i]  = bc[j] + b_hh[j];
        bz[i]  = bc[1024 + j] + b_hh[1024 + j];
        bni[i] = bc[2048 + j];
        bnh[i] = b_hh[2048 + j];
    }
    const size_t hoff = (size_t)(ct * 16384 + (b0 + gb) * 64 + gj4 * 2);
    char* sAh = (char*)hxA_hi + hoff; char* sAl = (char*)hxA_lo + hoff;
    char* sBh = (char*)hxB_hi + hoff; char* sBl = (char*)hxB_lo + hoff;
    const int g73 = gb * 73, g33 = gb * 33;

    int* flags = bar + bt * 128;   // 32 per-producer flags, 128B (coalesced)

    short8 bp[2][6];      // weight payload for a K64 granule, set = granule&1
    short8 ab[3][2][2];   // A-frag banks [granule%3][mh][hi/lo]
    f32x4 acc[2][3];      // [mh][{nt0,nt1,n-gate}]
    f32x4 acci[2];        // [mh] gi n-gate partial

#define ISSUE_A(BK, C)                                                        \
  { gl16c  (ab[BK][0][0], rh + (size_t)(C) * 16384);                          \
    gl16c_o(ab[BK][1][0], rh + (size_t)(C) * 16384);                          \
    gl16c  (ab[BK][0][1], rl + (size_t)(C) * 16384);                          \
    gl16c_o(ab[BK][1][1], rl + (size_t)(C) * 16384); }
#define GH_CHUNK(RB, BK)                                                      \
  { _Pragma("unroll")                                                         \
    for (int i_ = 0; i_ < 3; ++i_) {                                          \
        const int nt_ = (i_ < 2) ? (ntg * 2 + i_) : (4 + ntg);                \
        short8 bh_ = *(const short8*)(smB + (RB) + nt_ * 512 + foff);         \
        short8 bl_ = *(const short8*)(smB + (RB) + 3072 + nt_ * 512 + foff);  \
        f32x4 v0_ = mfma_(ab[BK][0][0], bh_, acc[0][i_]);                     \
        f32x4 v1_ = mfma_(ab[BK][1][0], bh_, acc[1][i_]);                     \
        v0_ = mfma_(ab[BK][0][0], bl_, v0_);                                  \
        v1_ = mfma_(ab[BK][1][0], bl_, v1_);                                  \
        v0_ = mfma_(ab[BK][0][1], bh_, v0_);                                  \
        v1_ = mfma_(ab[BK][1][1], bh_, v1_);                                  \
        acc[0][i_] = v0_; acc[1][i_] = v1_; } }

    #pragma unroll 1
    for (int t = 0; t < 256; ++t) {
        const char* rh = (t & 1) ? aBh : aAh;   // read planes (h in)
        const char* rl = (t & 1) ? aBl : aAl;
        char* wh = (t & 1) ? sAh : sBh;         // write planes (h out)
        char* wl = (t & 1) ? sAl : sBl;

        // ---- gi staging (h-independent; overlaps the coming spin) ----
        short8 gp[6];
        #pragma unroll
        for (int j = 0; j < 6; ++j)
            gl16(gp[j], cB[j % 3] + (j / 3) * 64);
        // x_t load + split for BOTH batch halves
        float xv[2][8];
        *(float4*)&xv[0][0] = *(const float4*)(xrow0 + (size_t)t * 64);
        *(float4*)&xv[0][4] = *(const float4*)(xrow0 + (size_t)t * 64 + 4);
        *(float4*)&xv[1][0] = *(const float4*)(xrow1 + (size_t)t * 64);
        *(float4*)&xv[1][4] = *(const float4*)(xrow1 + (size_t)t * 64 + 4);
        short8 xah[2], xal[2];
        #pragma unroll
        for (int m_ = 0; m_ < 2; ++m_)
            #pragma unroll
            for (int i = 0; i < 8; ++i) {
                unsigned short h = bf16hi(xv[m_][i]);
                ((short*)&xah[m_])[i] = (short)h;
                ((short*)&xal[m_])[i] = (short)bf16hi(xv[m_][i] - bf2f(h));
            }
        WAITV0();
        #pragma unroll
        for (int j = 0; j < 6; ++j)
            *(short8*)(smB + (j / 3) * 6144 + lo_[j % 3]) = gp[j];
        // issue w_hh granules 0 (chunks 0,1) and 1 (chunks 2,3) pre-spin
        #pragma unroll
        for (int j = 0; j < 6; ++j)
            gl16(bp[0][j], wB[j % 3] + (size_t)(j / 3) * 64);
        #pragma unroll
        for (int j = 0; j < 6; ++j)
            gl16(bp[1][j], wB[j % 3] + (size_t)(2 + j / 3) * 64);
        ABAR();
        // ---- gi compute (Wc chunk = kh): both mh, this wave's 3 nt ----
        {
            const int rb = kh * 6144;
            #pragma unroll
            for (int i_ = 0; i_ < 3; ++i_) {
                const int nt_ = (i_ < 2) ? (ntg * 2 + i_) : (4 + ntg);
                short8 bh_ = *(const short8*)(smB + rb + nt_ * 512 + foff);
                short8 bl_ = *(const short8*)(smB + rb + 3072 + nt_ * 512 + foff);
                #pragma unroll
                for (int m_ = 0; m_ < 2; ++m_) {
                    f32x4 z = {0.f, 0.f, 0.f, 0.f};
                    f32x4 v = mfma_(xah[m_], bh_, z);
                    v = mfma_(xah[m_], bl_, v);
                    v = mfma_(xal[m_], bh_, v);
                    if (i_ < 2) { acc[m_][i_] = v; }
                    else { acci[m_] = v; acc[m_][2] = z; }
                }
            }
        }
        // ---- wait for h(t): parallel poll of the 32 producer flags ----
        if (t > 0 && wid == 0) {
            int fl = (lane < 32)
                ? __hip_atomic_load(flags + lane, __ATOMIC_RELAXED,
                                    __HIP_MEMORY_SCOPE_SYSTEM)
                : t;
            while (__any(fl < t)) {
                __builtin_amdgcn_s_sleep(1);
                fl = (lane < 32)
                    ? __hip_atomic_load(flags + lane, __ATOMIC_RELAXED,
                                        __HIP_MEMORY_SCOPE_SYSTEM)
                    : t;
            }
        }
        ABAR();
        // ---- prologue: A(granule 0), write W0 -> buf0, A(granule 1) ----
        ISSUE_A(0, kh);
        WAITV10();                 // queue {W0(6),W1(6),A0(4)} -> forces W0
        #pragma unroll
        for (int j = 0; j < 6; ++j)
            *(short8*)(smB + (j / 3) * 6144 + lo_[j % 3]) = bp[0][j];
        ISSUE_A(1, 2 + kh);
        ABAR();
        // ---- gh pipeline: 16 K64 granules, ring-3, 1 barrier each ----
        #pragma unroll
        for (int G = 0; G < 16; ++G) {
            if (G <= 13) {
                #pragma unroll
                for (int j = 0; j < 6; ++j)
                    gl16(bp[G & 1][j],
                         wB[j % 3] + (size_t)(2 * G + 4 + j / 3) * 64);
                ISSUE_A((G + 2) % 3, 2 * (G + 2) + kh);
                WAITV14_T(ab[G % 3][0][0], ab[G % 3][0][1],
                          ab[G % 3][1][0], ab[G % 3][1][1]);
            } else if (G == 14) {
                WAITV4_T(ab[2][0][0], ab[2][0][1], ab[2][1][0], ab[2][1][1]);
            } else {
                WAITV0_T(ab[0][0][0], ab[0][0][1], ab[0][1][0], ab[0][1][1]);
            }
            if (G <= 14) {
                #pragma unroll
                for (int j = 0; j < 6; ++j)
                    *(short8*)(smB + ((G + 1) % 3) * 12288 + (j / 3) * 6144
                               + lo_[j % 3]) = bp[(G + 1) & 1][j];
                ABAR();
            }
            GH_CHUNK((G % 3) * 12288 + kh * 6144, G % 3);
        }
        __syncthreads();
        // ---- dump C fragments (aliased over ring bufs) ----
        {
            const int r0 = quad * 4;
            #pragma unroll
            for (int m_ = 0; m_ < 2; ++m_) {
                #pragma unroll
                for (int i_ = 0; i_ < 2; ++i_) {
                    const int nt_ = ntg * 2 + i_;
                    #pragma unroll
                    for (int r = 0; r < 4; ++r)
                        smF[kh * 2336 + (m_ * 16 + r0 + r) * 73 + nt_ * 16 + l15]
                            = acc[m_][i_][r];
                }
                #pragma unroll
                for (int r = 0; r < 4; ++r) {
                    smF[SHN_ + kh * 1056 + (m_ * 16 + r0 + r) * 33 + ntg * 16 + l15]
                        = acc[m_][2][r];
                    smF[SIN_ + kh * 1056 + (m_ * 16 + r0 + r) * 33 + ntg * 16 + l15]
                        = acci[m_][r];
                }
            }
        }
        __syncthreads();
        // ---- gate phase: thread owns (gb, gj4..+3); hprev in registers ----
        unsigned short ph4[4], pl4[4];
        #pragma unroll
        for (int i = 0; i < 4; ++i) {
            int cl = gj4 + i;
            float rp = smF[g73 + cl] + smF[2336 + g73 + cl] + br[i];
            float zp = smF[g73 + 32 + cl] + smF[2336 + g73 + 32 + cl] + bz[i];
            float ip = smF[SIN_ + g33 + cl] + smF[SIN_ + 1056 + g33 + cl] + bni[i];
            float hp = smF[SHN_ + g33 + cl] + smF[SHN_ + 1056 + g33 + cl] + bnh[i];
            float rr = sigmoidf_(rp);
            float zz = sigmoidf_(zp);
            float nn = tanhf_(ip + rr * hp);
            float hv = (1.0f - zz) * nn + zz * hreg[i];
            hreg[i] = hv;
            unsigned short hh = bf16hi(hv);
            ph4[i] = hh;
            pl4[i] = bf16hi(hv - bf2f(hh));
        }
        unsigned long long pk_hi =
            (unsigned long long)ph4[0] | ((unsigned long long)ph4[1] << 16) |
            ((unsigned long long)ph4[2] << 32) | ((unsigned long long)ph4[3] << 48);
        unsigned long long pk_lo =
            (unsigned long long)pl4[0] | ((unsigned long long)pl4[1] << 16) |
            ((unsigned long long)pl4[2] << 32) | ((unsigned long long)pl4[3] << 48);
        gs8c(wh, pk_hi);
        gs8c(wl, pk_lo);
        if (t == 255) {
            #pragma unroll
            for (int i = 0; i < 4; ++i)
                hn_out[(size_t)(b0 + gb) * HID_ + j0 + gj4 + i] = hreg[i];
        }
        WAITV0();           // h-plane stores at coherence point
        __syncthreads();    // whole block done
        if (t < 255 && tid == 0)
            __hip_atomic_store(flags + ct, t + 1, __ATOMIC_RELAXED,
                               __HIP_MEMORY_SCOPE_SYSTEM);
    }
#undef GH_CHUNK
#undef ISSUE_A
}

// ---------------- fc3: out3 = relu(relu(h) @ fc3_wT + fc3_b) --------------
__global__ __launch_bounds__(256) void k_fc3(
    const float* __restrict__ h, const float* __restrict__ fc3_w,
    const float* __restrict__ fc3_b, float* __restrict__ out3)
{
    const int bt = blockIdx.x >> 3;
    const int dt = blockIdx.x & 7;
    const int b0 = bt << 6;
    const int d0 = dt << 6;
    const int tid = threadIdx.x;
    const int tx = tid & 15, ty = tid >> 4;

    __shared__ float sh_h[64][36];
    __shared__ float sh_w[64][36];

    float acc[4][4] = {};
    const int lr = tid >> 3;
    const int lc = (tid & 7) << 2;

    for (int kk = 0; kk < HID_; kk += 32) {
        #pragma unroll
        for (int p = 0; p < 2; ++p) {
            int row = lr + (p << 5);
            float4 v = *(const float4*)(h + (size_t)(b0 + row) * HID_ + kk + lc);
            v.x = fmaxf(v.x, 0.f); v.y = fmaxf(v.y, 0.f);
            v.z = fmaxf(v.z, 0.f); v.w = fmaxf(v.w, 0.f);
            *(float4*)&sh_h[row][lc] = v;
            *(float4*)&sh_w[row][lc] =
                *(const float4*)(fc3_w + (size_t)(d0 + row) * HID_ + kk + lc);
        }
        __syncthreads();
        #pragma unroll
        for (int k = 0; k < 32; ++k) {
            float hv[4], wv[4];
            #pragma unroll
            for (int i = 0; i < 4; ++i) hv[i] = sh_h[ty + (i << 4)][k];
            #pragma unroll
            for (int q = 0; q < 4; ++q) wv[q] = sh_w[tx + (q << 4)][k];
            #pragma unroll
            for (int i = 0; i < 4; ++i)
                #pragma unroll
                for (int q = 0; q < 4; ++q)
                    acc[i][q] += hv[i] * wv[q];
        }
        __syncthreads();
    }
    #pragma unroll
    for (int i = 0; i < 4; ++i) {
        int b = b0 + ty + (i << 4);
        #pragma unroll
        for (int q = 0; q < 4; ++q) {
            int d = d0 + tx + (q << 4);
            out3[(size_t)b * D2 + d] = fmaxf(acc[i][q] + fc3_b[d], 0.f);
        }
    }
}

// ---------------- heads: params[b,o] = out3[b,:]·heads_w[cid[b],o,:]+b ----
__global__ __launch_bounds__(256) void k_heads(
    const float* __restrict__ out3, const int* __restrict__ cult,
    const float* __restrict__ hw, const float* __restrict__ hb,
    float* __restrict__ params)
{
    int b = blockIdx.x;
    int o = threadIdx.x >> 4;
    int l = threadIdx.x & 15;
    int cid = cult[b];
    const float* w = hw + ((size_t)cid * 16 + o) * D2;
    const float* x = out3 + (size_t)b * D2;
    float acc = 0.f;
    #pragma unroll
    for (int m = 0; m < 8; ++m) {
        int d4 = (l + (m << 4)) << 2;
        float4 xv = *(const float4*)(x + d4);
        float4 wv = *(const float4*)(w + d4);
        acc += xv.x * wv.x + xv.y * wv.y + xv.z * wv.z + xv.w * wv.w;
    }
    #pragma unroll
    for (int s = 1; s < 16; s <<= 1)
        acc += __shfl_xor(acc, s, 16);
    if (l == 0)
        params[(size_t)b * 16 + o] = acc + hb[(size_t)cid * 16 + o];
}

extern "C" void kernel_launch(void* const* d_in, const int* in_sizes, int n_in,
                              void* d_out, int out_size, void* d_ws, size_t ws_size,
                              hipStream_t stream)
{
    const float* input = (const float*)d_in[0];
    const float* hn    = (const float*)d_in[1];
    const int*   cult  = (const int*)d_in[2];
    const float* fc1_w = (const float*)d_in[3];
    const float* fc1_b = (const float*)d_in[4];
    const float* fc2_w = (const float*)d_in[5];
    const float* fc2_b = (const float*)d_in[6];
    const float* w_ih  = (const float*)d_in[7];
    const float* w_hh  = (const float*)d_in[8];
    const float* b_ih  = (const float*)d_in[9];
    const float* b_hh  = (const float*)d_in[10];
    const float* fc3_w = (const float*)d_in[11];
    const float* fc3_b = (const float*)d_in[12];
    const float* hw    = (const float*)d_in[13];
    const float* hb    = (const float*)d_in[14];
    float* out = (float*)d_out;
    float* hn_out = out + 4096;          // params 256*16, then hn 256*1024

    char* ws = (char*)d_ws;
    int*   bar    = (int*)ws;                                   // 4 KB
    float* W2     = (float*)(ws + 4096);                        // 256 KB
    float* b2     = (float*)(ws + 266240);
    float* bc     = (float*)(ws + 270336);
    unsigned short* whh_hi = (unsigned short*)(ws + 282624);    // 6 MB
    unsigned short* whh_lo = (unsigned short*)(ws + 282624 + 6291456);
    unsigned short* wc_hi  = (unsigned short*)(ws + 12865536);
    unsigned short* wc_lo  = (unsigned short*)(ws + 13258752);
    unsigned short* hxA_hi = (unsigned short*)(ws + 13651968);
    unsigned short* hxA_lo = (unsigned short*)(ws + 14176256);
    unsigned short* hxB_hi = (unsigned short*)(ws + 14700544);
    unsigned short* hxB_lo = (unsigned short*)(ws + 15224832);
    float* out3   = (float*)(ws + 15749120);                    // 512 KB

    hipMemsetAsync(bar, 0, 4096, stream);
    k_w2<<<256, 256, 0, stream>>>(fc2_w, fc1_w, fc1_b, fc2_b, W2, b2);
    k_wc<<<768, 256, 0, stream>>>(w_ih, W2, b2, b_ih, wc_hi, wc_lo, bc);
    k_splitw<<<3072, 256, 0, stream>>>(w_hh, whh_hi, whh_lo);
    k_split_h0<<<128, 256, 0, stream>>>(hn, hxA_hi, hxA_lo);
    k_gru<<<256, 256, 0, stream>>>(input, hn, b_hh, bc,
                                   whh_hi, whh_lo, wc_hi, wc_lo,
                                   hxA_hi, hxA_lo, hxB_hi, hxB_lo,
                                   hn_out, bar);
    k_fc3<<<32, 256, 0, stream>>>(hn_out, fc3_w, fc3_b, out3);
    k_heads<<<256, 256, 0, stream>>>(out3, cult, hw, hb, out);
}

// Round 11
// 2597.767 us; speedup vs baseline: 1.2862x; 1.2047x over previous
//
#include <hip/hip_runtime.h>

#define T_   256
#define HID_ 1024
#define D2   512

typedef __attribute__((ext_vector_type(8))) short  short8;
typedef __attribute__((ext_vector_type(8))) __bf16 bf16x8;
typedef __attribute__((ext_vector_type(4))) float  f32x4;

__device__ __forceinline__ float sigmoidf_(float x) {
    return __fdividef(1.0f, 1.0f + __expf(-x));
}
__device__ __forceinline__ float tanhf_(float x) {
    return 1.0f - __fdividef(2.0f, 1.0f + __expf(2.0f * x));
}
__device__ __forceinline__ unsigned short bf16hi(float x) {
    unsigned u = __float_as_uint(x);
    return (unsigned short)((u + 0x7FFFu + ((u >> 16) & 1u)) >> 16);
}
__device__ __forceinline__ float bf2f(unsigned short h) {
    return __uint_as_float((unsigned)h << 16);
}
__device__ __forceinline__ f32x4 mfma_(short8 a, short8 b, f32x4 c) {
    union { short8 s; bf16x8 b; } ua, ub;
    ua.s = a; ub.s = b;
    return __builtin_amdgcn_mfma_f32_16x16x32_bf16(ua.b, ub.b, c, 0, 0, 0);
}

// ---- raw asm memory ops (64-bit VGPR address form: works for divergent ptrs)
__device__ __forceinline__ void gl16(short8& d, const void* p) {
    asm volatile("global_load_dwordx4 %0, %1, off" : "=v"(d) : "v"(p));
}
__device__ __forceinline__ void gl16c(short8& d, const void* p) {
    asm volatile("global_load_dwordx4 %0, %1, off sc0 sc1" : "=v"(d) : "v"(p));
}
__device__ __forceinline__ void gs4c(void* p, unsigned v) {
    asm volatile("global_store_dword %0, %1, off sc0 sc1"
                 :: "v"(p), "v"(v) : "memory");
}
#define WAITV0() asm volatile("s_waitcnt vmcnt(0)" ::: "memory")
#define WAITV5() asm volatile("s_waitcnt vmcnt(5)" ::: "memory")
// ties "materialize" the A-frag regs so MFMAs can't be hoisted above the wait
#define WAITV7_T(H, L) asm volatile("s_waitcnt vmcnt(7)" : "+v"(H), "+v"(L) :: "memory")
#define WAITV2_T(H, L) asm volatile("s_waitcnt vmcnt(2)" : "+v"(H), "+v"(L) :: "memory")
#define WAITV0_T(H, L) asm volatile("s_waitcnt vmcnt(0)" : "+v"(H), "+v"(L) :: "memory")
#define ABAR() asm volatile("s_waitcnt lgkmcnt(0)\n\ts_barrier" ::: "memory")

// ---------------- prelim: W2 = fc2_w @ fc1_w, b2 = fc2_w@fc1_b + fc2_b ----
__global__ __launch_bounds__(256) void k_w2(
    const float* __restrict__ fc2_w, const float* __restrict__ fc1_w,
    const float* __restrict__ fc1_b, const float* __restrict__ fc2_b,
    float* __restrict__ W2, float* __restrict__ b2)
{
    int idx = blockIdx.x * 256 + threadIdx.x;   // 0..65535
    int r = idx >> 6, c = idx & 63;
    float acc = 0.f;
    for (int k = 0; k < D2; ++k)
        acc += fc2_w[(size_t)r * D2 + k] * fc1_w[(size_t)k * 64 + c];
    W2[idx] = acc;
    if (c == 0) {
        float a = fc2_b[r];
        for (int k = 0; k < D2; ++k)
            a += fc2_w[(size_t)r * D2 + k] * fc1_b[k];
        b2[r] = a;
    }
}

// -------- prelim: Wc = w_ih @ W2 (bf16 split planes), bc = w_ih@b2 + b_ih --
__global__ __launch_bounds__(256) void k_wc(
    const float* __restrict__ w_ih, const float* __restrict__ W2,
    const float* __restrict__ b2, const float* __restrict__ b_ih,
    unsigned short* __restrict__ wc_hi, unsigned short* __restrict__ wc_lo,
    float* __restrict__ bc)
{
    int idx = blockIdx.x * 256 + threadIdx.x;   // 0..196607
    int r = idx >> 6, c = idx & 63;
    float acc = 0.f;
    for (int k = 0; k < HID_; ++k)
        acc += w_ih[(size_t)r * HID_ + k] * W2[(size_t)k * 64 + c];
    unsigned short h = bf16hi(acc);
    wc_hi[idx] = h;
    wc_lo[idx] = bf16hi(acc - bf2f(h));
    if (c == 0) {
        float a = b_ih[r];
        for (int k = 0; k < HID_; ++k)
            a += w_ih[(size_t)r * HID_ + k] * b2[k];
        bc[r] = a;
    }
}

// ---------------- prelim: split w_hh into bf16 hi/lo planes ----------------
__global__ __launch_bounds__(256) void k_splitw(
    const float* __restrict__ w, unsigned short* __restrict__ hi,
    unsigned short* __restrict__ lo)
{
    int i4 = (blockIdx.x * 256 + threadIdx.x) * 4;
    float4 v = *(const float4*)(w + i4);
    float vv[4] = {v.x, v.y, v.z, v.w};
    unsigned short h4[4], l4[4];
    #pragma unroll
    for (int i = 0; i < 4; ++i) {
        h4[i] = bf16hi(vv[i]);
        l4[i] = bf16hi(vv[i] - bf2f(h4[i]));
    }
    *(unsigned long long*)(hi + i4) =
        (unsigned long long)h4[0] | ((unsigned long long)h4[1] << 16) |
        ((unsigned long long)h4[2] << 32) | ((unsigned long long)h4[3] << 48);
    *(unsigned long long*)(lo + i4) =
        (unsigned long long)l4[0] | ((unsigned long long)l4[1] << 16) |
        ((unsigned long long)l4[2] << 32) | ((unsigned long long)l4[3] << 48);
}

// ------- prelim: h0 -> bf16 split planes in fragment-granule layout --------
// layout: byte = (k>>5)*16384 + b*64 + ((k>>3)&3)*16 + (k&7)*2
__global__ __launch_bounds__(256) void k_split_h0(
    const float* __restrict__ hn, unsigned short* __restrict__ hi,
    unsigned short* __restrict__ lo)
{
    int gid = blockIdx.x * 256 + threadIdx.x;      // 0..32767
    int b = gid >> 7, kseg = gid & 127;
    const float* src = hn + (size_t)b * HID_ + kseg * 8;
    short8 h8, l8;
    #pragma unroll
    for (int i = 0; i < 8; ++i) {
        float v = src[i];
        unsigned short h = bf16hi(v);
        ((short*)&h8)[i] = (short)h;
        ((short*)&l8)[i] = (short)bf16hi(v - bf2f(h));
    }
    size_t off = (size_t)(kseg >> 2) * 8192 + b * 32 + (kseg & 3) * 8; // ushorts
    *(short8*)(hi + off) = h8;
    *(short8*)(lo + off) = l8;
}

// ---------------- main persistent GRU kernel (MFMA split-bf16) -------------
// R10: occupancy doubling. 512 blocks (ct 0..63 x bt 0..7), 16 h-cols per
// block, 2 blocks/CU (__launch_bounds__(256,2); LDS 36864B/block). All
// intra-block pipelining levers are exhausted (R6/R8 regressed, R9 neutral)
// and nothing is >18% utilized: the floor is EXPOSED latency at 1 wave/SIMD.
// Two co-resident blocks at independent phases overlap barrier drains, L3
// A-load latency, and the inter-block spin with the other block's MFMAs.
// Structure per block = R5's proven scheme scaled to 16 cols: 3 nt tiles
// (r/z/n), ring-3 of 6144-short granule bufs, (mh,kh) wave map, K=64
// granules, 15 intra-step ABARs. Per-column accumulation chains unchanged
// (same chunk order per kh, same 3-mfma order, same kh0+kh1 gate sums) ->
// bitwise-identical output. vmcnt ledger (W=3 loads/granule, A=2):
//   pre-spin: gi(3)+x drained by WAITV0; issue W0(3), W1(3). ABAR. gi-comp.
//   post-spin: A0(2); vmcnt(5) forces W0; write W0->buf0; A1(2); ABAR.
//   iter G<=13: issue W(G+2)(3) into bp[G&1], A(G+2)(2) into bank (G+2)%3;
//     vmcnt(7) forces exactly {W(G+1), A(G)} (A flies 2 intervals -> L3
//     covered); write W(G+1)->buf (G+1)%3; ABAR; compute chunk 2G+kh.
//   G=14: vmcnt(2) {W15,A14}; write W15->buf0; ABAR.  G=15: vmcnt(0).
__global__ __launch_bounds__(256, 2) void k_gru(
    const float* __restrict__ input,
    const float* __restrict__ hn,
    const float* __restrict__ b_hh,
    const float* __restrict__ bc,
    const unsigned short* __restrict__ whh_hi,
    const unsigned short* __restrict__ whh_lo,
    const unsigned short* __restrict__ wc_hi,
    const unsigned short* __restrict__ wc_lo,
    unsigned short* __restrict__ hxA_hi, unsigned short* __restrict__ hxA_lo,
    unsigned short* __restrict__ hxB_hi, unsigned short* __restrict__ hxB_lo,
    float* __restrict__ hn_out,
    int* __restrict__ bar)
{
    const int g = blockIdx.x, ct = g & 63, bt = g >> 6;
    const int j0 = ct << 4, b0 = bt << 5;
    const int tid = threadIdx.x, lane = tid & 63, wid = tid >> 6;
    const int mh = wid & 1, kh = wid >> 1;
    const int l15 = lane & 15, quad = lane >> 4;

    __shared__ short smB[18432];              // 3 ring bufs x 6144 shorts
    float* smF = (float*)smB;                 // C-dump alias (post-K-loop)
    const int SIN_ = 2112, SHN_ = 3200;

    // ---- staging descriptors: 3 x 16B segs per thread per K64 granule ----
    // granule buf = 2 chunks x (96 rows x 32 shorts); row = pl*48 + n,
    // n = gate*16 + col16. seg = tid + i*256 in [0,768).
    const char* wB[3]; const char* cB[3]; int lo_[3];
    #pragma unroll
    for (int i = 0; i < 3; ++i) {
        int seg = tid + (i << 8);
        int cg = seg / 384, s = seg % 384;
        int row = s >> 2, ss = s & 3;
        int pln = row / 48, n = row % 48;
        int grow = (n >> 4) * HID_ + j0 + (n & 15);
        wB[i] = (const char*)(pln ? whh_lo : whh_hi)
              + (size_t)grow * 2048u + (size_t)(ss * 16 + cg * 64);
        cB[i] = (const char*)(pln ? wc_lo : wc_hi)
              + (size_t)grow * 128u + (size_t)(ss * 16 + cg * 64);
        lo_[i] = cg * 3072 + row * 32 + ((ss * 8) ^ (((row >> 1) & 3) << 3));
    }
    const int foff = l15 * 32 + ((quad * 8) ^ (((l15 >> 1) & 3) << 3));   // swz
    const size_t aoff = (size_t)((b0 + mh * 16 + l15) * 64 + quad * 16);
    const char* aAh = (const char*)hxA_hi + aoff;
    const char* aAl = (const char*)hxA_lo + aoff;
    const char* aBh = (const char*)hxB_hi + aoff;
    const char* aBl = (const char*)hxB_lo + aoff;
    const float* xrow = input + (size_t)(b0 + mh * 16 + l15) * (T_ * 64)
                              + kh * 32 + quad * 8;

    // ---- gate-phase statics: thread owns (b = b0+gb, j = j0+gj2, +1) -----
    const int gb = tid >> 3, gj2 = (tid & 7) << 1;
    float hreg[2], br[2], bz[2], bni[2], bnh[2];
    #pragma unroll
    for (int i = 0; i < 2; ++i) {
        int j = j0 + gj2 + i;
        hreg[i] = hn[(size_t)(b0 + gb) * HID_ + j];
        br[i]  = bc[j] + b_hh[j];
        bz[i]  = bc[1024 + j] + b_hh[1024 + j];
        bni[i] = bc[2048 + j];
        bnh[i] = b_hh[2048 + j];
    }
    const int j2 = j0 + gj2;
    const size_t hoff = (size_t)(j2 >> 5) * 16384 + (size_t)(b0 + gb) * 64
                      + (size_t)((j2 >> 3) & 3) * 16 + (size_t)(j2 & 7) * 2;
    char* sAh = (char*)hxA_hi + hoff; char* sAl = (char*)hxA_lo + hoff;
    char* sBh = (char*)hxB_hi + hoff; char* sBl = (char*)hxB_lo + hoff;
    const int g33 = gb * 33, g17 = gb * 17;

    int* flags = bar + bt * 128;   // 64 per-producer flags, 256B (coalesced)

    short8 bp[2][3];   // weight payload for a K64 granule, set = granule&1
    short8 ab[3][2];   // A-frag banks [granule%3][hi/lo]
    f32x4 acc[3];      // r, z, n(gh)
    f32x4 acci;        // n(gi)

#define ISSUE_A(BK, C)                                                       \
  { gl16c(ab[BK][0], rh + (size_t)(C) * 16384);                              \
    gl16c(ab[BK][1], rl + (size_t)(C) * 16384); }
#define GH_CHUNK(RB, AH, AL)                                                 \
  { _Pragma("unroll")                                                        \
    for (int nt = 0; nt < 3; ++nt) {                                         \
        short8 bh_ = *(const short8*)(smB + (RB) + nt * 512 + foff);         \
        short8 bl_ = *(const short8*)(smB + (RB) + 1536 + nt * 512 + foff);  \
        f32x4 v_ = mfma_(AH, bh_, acc[nt]);                                  \
        v_ = mfma_(AH, bl_, v_);                                             \
        v_ = mfma_(AL, bh_, v_);                                             \
        acc[nt] = v_; } }

    #pragma unroll 1
    for (int t = 0; t < 256; ++t) {
        const char* rh = (t & 1) ? aBh : aAh;   // read planes (h in)
        const char* rl = (t & 1) ? aBl : aAl;
        char* wh = (t & 1) ? sAh : sBh;         // write planes (h out)
        char* wl = (t & 1) ? sAl : sBl;

        // ---- gi staging (h-independent; overlaps the coming spin) ----
        short8 gp[3];
        #pragma unroll
        for (int j = 0; j < 3; ++j)
            gl16(gp[j], cB[j]);
        // x_t load + split (plain cached loads; compiler-managed waits)
        float xv[8];
        *(float4*)&xv[0] = *(const float4*)(xrow + (size_t)t * 64);
        *(float4*)&xv[4] = *(const float4*)(xrow + (size_t)t * 64 + 4);
        short8 xa_hi, xa_lo;
        #pragma unroll
        for (int i = 0; i < 8; ++i) {
            unsigned short h = bf16hi(xv[i]);
            ((short*)&xa_hi)[i] = (short)h;
            ((short*)&xa_lo)[i] = (short)bf16hi(xv[i] - bf2f(h));
        }
        WAITV0();
        #pragma unroll
        for (int j = 0; j < 3; ++j)
            *(short8*)(smB + lo_[j]) = gp[j];
        // issue w_hh granules 0 and 1 pre-spin (weights step-invariant)
        #pragma unroll
        for (int j = 0; j < 3; ++j)
            gl16(bp[0][j], wB[j]);
        #pragma unroll
        for (int j = 0; j < 3; ++j)
            gl16(bp[1][j], wB[j] + 128);
        ABAR();
        // ---- gi compute (Wc chunk = kh), inits accumulators ----
        {
            const int rb = kh * 3072;
            #pragma unroll
            for (int nt = 0; nt < 3; ++nt) {
                short8 bh_ = *(const short8*)(smB + rb + nt * 512 + foff);
                short8 bl_ = *(const short8*)(smB + rb + 1536 + nt * 512 + foff);
                f32x4 z = {0.f, 0.f, 0.f, 0.f};
                f32x4 v = mfma_(xa_hi, bh_, z);
                v = mfma_(xa_hi, bl_, v);
                v = mfma_(xa_lo, bh_, v);
                if (nt < 2) { acc[nt] = v; }
                else { acci = v; acc[2] = z; }
            }
        }
        // ---- wait for h(t): parallel poll of the 64 producer flags ----
        if (t > 0 && wid == 0) {
            int fl = __hip_atomic_load(flags + lane, __ATOMIC_RELAXED,
                                       __HIP_MEMORY_SCOPE_SYSTEM);
            while (__any(fl < t)) {
                __builtin_amdgcn_s_sleep(1);
                fl = __hip_atomic_load(flags + lane, __ATOMIC_RELAXED,
                                       __HIP_MEMORY_SCOPE_SYSTEM);
            }
        }
        ABAR();
        // ---- prologue: A(granule 0), write W0 -> buf0, A(granule 1) ----
        ISSUE_A(0, kh);
        WAITV5();                  // queue {W0(3),W1(3),A0(2)} -> forces W0
        #pragma unroll
        for (int j = 0; j < 3; ++j)
            *(short8*)(smB + lo_[j]) = bp[0][j];
        ISSUE_A(1, 2 + kh);
        ABAR();
        // ---- gh pipeline: 16 K64 granules, ring-3, 1 barrier each ----
        #pragma unroll
        for (int G = 0; G < 16; ++G) {
            if (G <= 13) {
                #pragma unroll
                for (int j = 0; j < 3; ++j)
                    gl16(bp[G & 1][j], wB[j] + (size_t)(G + 2) * 128);
                ISSUE_A((G + 2) % 3, 2 * (G + 2) + kh);
                WAITV7_T(ab[G % 3][0], ab[G % 3][1]);
            } else if (G == 14) {
                WAITV2_T(ab[2][0], ab[2][1]);
            } else {
                WAITV0_T(ab[0][0], ab[0][1]);
            }
            if (G <= 14) {
                #pragma unroll
                for (int j = 0; j < 3; ++j)
                    *(short8*)(smB + ((G + 1) % 3) * 6144 + lo_[j])
                        = bp[(G + 1) & 1][j];
                ABAR();
            }
            GH_CHUNK((G % 3) * 6144 + kh * 3072, ab[G % 3][0], ab[G % 3][1]);
        }
        __syncthreads();
        // ---- dump C fragments (aliased over ring bufs) ----
        {
            const int row = mh * 16 + quad * 4;
            #pragma unroll
            for (int nt = 0; nt < 2; ++nt)
                #pragma unroll
                for (int r = 0; r < 4; ++r)
                    smF[kh * 1056 + (row + r) * 33 + nt * 16 + l15] = acc[nt][r];
            #pragma unroll
            for (int r = 0; r < 4; ++r) {
                smF[SHN_ + kh * 544 + (row + r) * 17 + l15] = acc[2][r];
                smF[SIN_ + kh * 544 + (row + r) * 17 + l15] = acci[r];
            }
        }
        __syncthreads();
        // ---- gate phase: thread owns (gb, gj2, +1); hprev in registers ----
        unsigned short ph2[2], pl2[2];
        #pragma unroll
        for (int i = 0; i < 2; ++i) {
            int cl = gj2 + i;
            float rp = smF[g33 + cl] + smF[1056 + g33 + cl] + br[i];
            float zp = smF[g33 + 16 + cl] + smF[1056 + g33 + 16 + cl] + bz[i];
            float ip = smF[SIN_ + g17 + cl] + smF[SIN_ + 544 + g17 + cl] + bni[i];
            float hp = smF[SHN_ + g17 + cl] + smF[SHN_ + 544 + g17 + cl] + bnh[i];
            float rr = sigmoidf_(rp);
            float zz = sigmoidf_(zp);
            float nn = tanhf_(ip + rr * hp);
            float hv = (1.0f - zz) * nn + zz * hreg[i];
            hreg[i] = hv;
            unsigned short hh = bf16hi(hv);
            ph2[i] = hh;
            pl2[i] = bf16hi(hv - bf2f(hh));
        }
        unsigned pk_hi = (unsigned)ph2[0] | ((unsigned)ph2[1] << 16);
        unsigned pk_lo = (unsigned)pl2[0] | ((unsigned)pl2[1] << 16);
        gs4c(wh, pk_hi);
        gs4c(wl, pk_lo);
        if (t == 255) {
            #pragma unroll
            for (int i = 0; i < 2; ++i)
                hn_out[(size_t)(b0 + gb) * HID_ + j0 + gj2 + i] = hreg[i];
        }
        WAITV0();           // h-plane stores at coherence point
        __syncthreads();    // whole block done
        if (t < 255 && tid == 0)
            __hip_atomic_store(flags + ct, t + 1, __ATOMIC_RELAXED,
                               __HIP_MEMORY_SCOPE_SYSTEM);
    }
#undef GH_CHUNK
#undef ISSUE_A
}

// ---------------- fc3: out3 = relu(relu(h) @ fc3_wT + fc3_b) --------------
__global__ __launch_bounds__(256) void k_fc3(
    const float* __restrict__ h, const float* __restrict__ fc3_w,
    const float* __restrict__ fc3_b, float* __restrict__ out3)
{
    const int bt = blockIdx.x >> 3;
    const int dt = blockIdx.x & 7;
    const int b0 = bt << 6;
    const int d0 = dt << 6;
    const int tid = threadIdx.x;
    const int tx = tid & 15, ty = tid >> 4;

    __shared__ float sh_h[64][36];
    __shared__ float sh_w[64][36];

    float acc[4][4] = {};
    const int lr = tid >> 3;
    const int lc = (tid & 7) << 2;

    for (int kk = 0; kk < HID_; kk += 32) {
        #pragma unroll
        for (int p = 0; p < 2; ++p) {
            int row = lr + (p << 5);
            float4 v = *(const float4*)(h + (size_t)(b0 + row) * HID_ + kk + lc);
            v.x = fmaxf(v.x, 0.f); v.y = fmaxf(v.y, 0.f);
            v.z = fmaxf(v.z, 0.f); v.w = fmaxf(v.w, 0.f);
            *(float4*)&sh_h[row][lc] = v;
            *(float4*)&sh_w[row][lc] =
                *(const float4*)(fc3_w + (size_t)(d0 + row) * HID_ + kk + lc);
        }
        __syncthreads();
        #pragma unroll
        for (int k = 0; k < 32; ++k) {
            float hv[4], wv[4];
            #pragma unroll
            for (int i = 0; i < 4; ++i) hv[i] = sh_h[ty + (i << 4)][k];
            #pragma unroll
            for (int q = 0; q < 4; ++q) wv[q] = sh_w[tx + (q << 4)][k];
            #pragma unroll
            for (int i = 0; i < 4; ++i)
                #pragma unroll
                for (int q = 0; q < 4; ++q)
                    acc[i][q] += hv[i] * wv[q];
        }
        __syncthreads();
    }
    #pragma unroll
    for (int i = 0; i < 4; ++i) {
        int b = b0 + ty + (i << 4);
        #pragma unroll
        for (int q = 0; q < 4; ++q) {
            int d = d0 + tx + (q << 4);
            out3[(size_t)b * D2 + d] = fmaxf(acc[i][q] + fc3_b[d], 0.f);
        }
    }
}

// ---------------- heads: params[b,o] = out3[b,:]·heads_w[cid[b],o,:]+b ----
__global__ __launch_bounds__(256) void k_heads(
    const float* __restrict__ out3, const int* __restrict__ cult,
    const float* __restrict__ hw, const float* __restrict__ hb,
    float* __restrict__ params)
{
    int b = blockIdx.x;
    int o = threadIdx.x >> 4;
    int l = threadIdx.x & 15;
    int cid = cult[b];
    const float* w = hw + ((size_t)cid * 16 + o) * D2;
    const float* x = out3 + (size_t)b * D2;
    float acc = 0.f;
    #pragma unroll
    for (int m = 0; m < 8; ++m) {
        int d4 = (l + (m << 4)) << 2;
        float4 xv = *(const float4*)(x + d4);
        float4 wv = *(const float4*)(w + d4);
        acc += xv.x * wv.x + xv.y * wv.y + xv.z * wv.z + xv.w * wv.w;
    }
    #pragma unroll
    for (int s = 1; s < 16; s <<= 1)
        acc += __shfl_xor(acc, s, 16);
    if (l == 0)
        params[(size_t)b * 16 + o] = acc + hb[(size_t)cid * 16 + o];
}

extern "C" void kernel_launch(void* const* d_in, const int* in_sizes, int n_in,
                              void* d_out, int out_size, void* d_ws, size_t ws_size,
                              hipStream_t stream)
{
    const float* input = (const float*)d_in[0];
    const float* hn    = (const float*)d_in[1];
    const int*   cult  = (const int*)d_in[2];
    const float* fc1_w = (const float*)d_in[3];
    const float* fc1_b = (const float*)d_in[4];
    const float* fc2_w = (const float*)d_in[5];
    const float* fc2_b = (const float*)d_in[6];
    const float* w_ih  = (const float*)d_in[7];
    const float* w_hh  = (const float*)d_in[8];
    const float* b_ih  = (const float*)d_in[9];
    const float* b_hh  = (const float*)d_in[10];
    const float* fc3_w = (const float*)d_in[11];
    const float* fc3_b = (const float*)d_in[12];
    const float* hw    = (const float*)d_in[13];
    const float* hb    = (const float*)d_in[14];
    float* out = (float*)d_out;
    float* hn_out = out + 4096;          // params 256*16, then hn 256*1024

    char* ws = (char*)d_ws;
    int*   bar    = (int*)ws;                                   // 4 KB
    float* W2     = (float*)(ws + 4096);                        // 256 KB
    float* b2     = (float*)(ws + 266240);
    float* bc     = (float*)(ws + 270336);
    unsigned short* whh_hi = (unsigned short*)(ws + 282624);    // 6 MB
    unsigned short* whh_lo = (unsigned short*)(ws + 282624 + 6291456);
    unsigned short* wc_hi  = (unsigned short*)(ws + 12865536);
    unsigned short* wc_lo  = (unsigned short*)(ws + 13258752);
    unsigned short* hxA_hi = (unsigned short*)(ws + 13651968);
    unsigned short* hxA_lo = (unsigned short*)(ws + 14176256);
    unsigned short* hxB_hi = (unsigned short*)(ws + 14700544);
    unsigned short* hxB_lo = (unsigned short*)(ws + 15224832);
    float* out3   = (float*)(ws + 15749120);                    // 512 KB

    hipMemsetAsync(bar, 0, 4096, stream);
    k_w2<<<256, 256, 0, stream>>>(fc2_w, fc1_w, fc1_b, fc2_b, W2, b2);
    k_wc<<<768, 256, 0, stream>>>(w_ih, W2, b2, b_ih, wc_hi, wc_lo, bc);
    k_splitw<<<3072, 256, 0, stream>>>(w_hh, whh_hi, whh_lo);
    k_split_h0<<<128, 256, 0, stream>>>(hn, hxA_hi, hxA_lo);
    k_gru<<<512, 256, 0, stream>>>(input, hn, b_hh, bc,
                                   whh_hi, whh_lo, wc_hi, wc_lo,
                                   hxA_hi, hxA_lo, hxB_hi, hxB_lo,
                                   hn_out, bar);
    k_fc3<<<32, 256, 0, stream>>>(hn_out, fc3_w, fc3_b, out3);
    k_heads<<<256, 256, 0, stream>>>(out3, cult, hw, hb, out);
}

// Round 12
// 2579.059 us; speedup vs baseline: 1.2955x; 1.0073x over previous
//
#include <hip/hip_runtime.h>

#define T_   256
#define HID_ 1024
#define D2   512

typedef __attribute__((ext_vector_type(8))) short  short8;
typedef __attribute__((ext_vector_type(8))) __bf16 bf16x8;
typedef __attribute__((ext_vector_type(4))) float  f32x4;

__device__ __forceinline__ float sigmoidf_(float x) {
    return __fdividef(1.0f, 1.0f + __expf(-x));
}
__device__ __forceinline__ float tanhf_(float x) {
    return 1.0f - __fdividef(2.0f, 1.0f + __expf(2.0f * x));
}
__device__ __forceinline__ unsigned short bf16hi(float x) {
    unsigned u = __float_as_uint(x);
    return (unsigned short)((u + 0x7FFFu + ((u >> 16) & 1u)) >> 16);
}
__device__ __forceinline__ float bf2f(unsigned short h) {
    return __uint_as_float((unsigned)h << 16);
}
__device__ __forceinline__ f32x4 mfma_(short8 a, short8 b, f32x4 c) {
    union { short8 s; bf16x8 b; } ua, ub;
    ua.s = a; ub.s = b;
    return __builtin_amdgcn_mfma_f32_16x16x32_bf16(ua.b, ub.b, c, 0, 0, 0);
}

// ---- raw asm memory ops (64-bit VGPR address form: works for divergent ptrs)
__device__ __forceinline__ void gl16(short8& d, const void* p) {
    asm volatile("global_load_dwordx4 %0, %1, off" : "=v"(d) : "v"(p));
}
__device__ __forceinline__ void gl16c(short8& d, const void* p) {
    asm volatile("global_load_dwordx4 %0, %1, off sc0 sc1" : "=v"(d) : "v"(p));
}
__device__ __forceinline__ void gs4c(void* p, unsigned v) {
    asm volatile("global_store_dword %0, %1, off sc0 sc1"
                 :: "v"(p), "v"(v) : "memory");
}
#define WAITV0() asm volatile("s_waitcnt vmcnt(0)" ::: "memory")
#define WAITV5() asm volatile("s_waitcnt vmcnt(5)" ::: "memory")
// ties "materialize" the A-frag regs so MFMAs can't be hoisted above the wait
#define WAITV7_T(H, L) asm volatile("s_waitcnt vmcnt(7)" : "+v"(H), "+v"(L) :: "memory")
#define WAITV2_T(H, L) asm volatile("s_waitcnt vmcnt(2)" : "+v"(H), "+v"(L) :: "memory")
#define WAITV0_T(H, L) asm volatile("s_waitcnt vmcnt(0)" : "+v"(H), "+v"(L) :: "memory")
#define ABAR() asm volatile("s_waitcnt lgkmcnt(0)\n\ts_barrier" ::: "memory")

// ---------------- prelim: W2 = fc2_w @ fc1_w, b2 = fc2_w@fc1_b + fc2_b ----
__global__ __launch_bounds__(256) void k_w2(
    const float* __restrict__ fc2_w, const float* __restrict__ fc1_w,
    const float* __restrict__ fc1_b, const float* __restrict__ fc2_b,
    float* __restrict__ W2, float* __restrict__ b2)
{
    int idx = blockIdx.x * 256 + threadIdx.x;   // 0..65535
    int r = idx >> 6, c = idx & 63;
    float acc = 0.f;
    for (int k = 0; k < D2; ++k)
        acc += fc2_w[(size_t)r * D2 + k] * fc1_w[(size_t)k * 64 + c];
    W2[idx] = acc;
    if (c == 0) {
        float a = fc2_b[r];
        for (int k = 0; k < D2; ++k)
            a += fc2_w[(size_t)r * D2 + k] * fc1_b[k];
        b2[r] = a;
    }
}

// -------- prelim: Wc = w_ih @ W2 (bf16 split planes), bc = w_ih@b2 + b_ih --
__global__ __launch_bounds__(256) void k_wc(
    const float* __restrict__ w_ih, const float* __restrict__ W2,
    const float* __restrict__ b2, const float* __restrict__ b_ih,
    unsigned short* __restrict__ wc_hi, unsigned short* __restrict__ wc_lo,
    float* __restrict__ bc)
{
    int idx = blockIdx.x * 256 + threadIdx.x;   // 0..196607
    int r = idx >> 6, c = idx & 63;
    float acc = 0.f;
    for (int k = 0; k < HID_; ++k)
        acc += w_ih[(size_t)r * HID_ + k] * W2[(size_t)k * 64 + c];
    unsigned short h = bf16hi(acc);
    wc_hi[idx] = h;
    wc_lo[idx] = bf16hi(acc - bf2f(h));
    if (c == 0) {
        float a = b_ih[r];
        for (int k = 0; k < HID_; ++k)
            a += w_ih[(size_t)r * HID_ + k] * b2[k];
        bc[r] = a;
    }
}

// ---------------- prelim: split w_hh into bf16 hi/lo planes ----------------
__global__ __launch_bounds__(256) void k_splitw(
    const float* __restrict__ w, unsigned short* __restrict__ hi,
    unsigned short* __restrict__ lo)
{
    int i4 = (blockIdx.x * 256 + threadIdx.x) * 4;
    float4 v = *(const float4*)(w + i4);
    float vv[4] = {v.x, v.y, v.z, v.w};
    unsigned short h4[4], l4[4];
    #pragma unroll
    for (int i = 0; i < 4; ++i) {
        h4[i] = bf16hi(vv[i]);
        l4[i] = bf16hi(vv[i] - bf2f(h4[i]));
    }
    *(unsigned long long*)(hi + i4) =
        (unsigned long long)h4[0] | ((unsigned long long)h4[1] << 16) |
        ((unsigned long long)h4[2] << 32) | ((unsigned long long)h4[3] << 48);
    *(unsigned long long*)(lo + i4) =
        (unsigned long long)l4[0] | ((unsigned long long)l4[1] << 16) |
        ((unsigned long long)l4[2] << 32) | ((unsigned long long)l4[3] << 48);
}

// ------- prelim: h0 -> bf16 split planes in fragment-granule layout --------
// layout: byte = (k>>5)*16384 + b*64 + ((k>>3)&3)*16 + (k&7)*2
__global__ __launch_bounds__(256) void k_split_h0(
    const float* __restrict__ hn, unsigned short* __restrict__ hi,
    unsigned short* __restrict__ lo)
{
    int gid = blockIdx.x * 256 + threadIdx.x;      // 0..32767
    int b = gid >> 7, kseg = gid & 127;
    const float* src = hn + (size_t)b * HID_ + kseg * 8;
    short8 h8, l8;
    #pragma unroll
    for (int i = 0; i < 8; ++i) {
        float v = src[i];
        unsigned short h = bf16hi(v);
        ((short*)&h8)[i] = (short)h;
        ((short*)&l8)[i] = (short)bf16hi(v - bf2f(h));
    }
    size_t off = (size_t)(kseg >> 2) * 8192 + b * 32 + (kseg & 3) * 8; // ushorts
    *(short8*)(hi + off) = h8;
    *(short8*)(lo + off) = l8;
}

// ---------------- main persistent GRU kernel (MFMA split-bf16) -------------
// R11 (on R10's 2-blocks/CU structure, which was +17%): Wc is step-invariant
// but R10 re-staged it into LDS EVERY step (192 ds_write-instr/block-step,
// ~17% of all LDS instructions, + 768 L2 loads + one barrier for its
// visibility). Now Wc is loaded ONCE into a permanent 12288B LDS region
// before the t-loop; gi compute reads it directly. The first per-step ABAR
// (whose only job was gi-write visibility) is removed. vmcnt ledger is
// unchanged (pre-spin queue at WAITV5 is still exactly {W0(3),W1(3),A0(2)}).
// Same fragment values, different LDS address -> bitwise-identical output.
// LDS/block 36864 -> 49152B; 2 blocks/CU = 98304 <= 160K.
__global__ __launch_bounds__(256, 2) void k_gru(
    const float* __restrict__ input,
    const float* __restrict__ hn,
    const float* __restrict__ b_hh,
    const float* __restrict__ bc,
    const unsigned short* __restrict__ whh_hi,
    const unsigned short* __restrict__ whh_lo,
    const unsigned short* __restrict__ wc_hi,
    const unsigned short* __restrict__ wc_lo,
    unsigned short* __restrict__ hxA_hi, unsigned short* __restrict__ hxA_lo,
    unsigned short* __restrict__ hxB_hi, unsigned short* __restrict__ hxB_lo,
    float* __restrict__ hn_out,
    int* __restrict__ bar)
{
    const int g = blockIdx.x, ct = g & 63, bt = g >> 6;
    const int j0 = ct << 4, b0 = bt << 5;
    const int tid = threadIdx.x, lane = tid & 63, wid = tid >> 6;
    const int mh = wid & 1, kh = wid >> 1;
    const int l15 = lane & 15, quad = lane >> 4;

    __shared__ short smB[24576];   // 3 ring bufs x 6144 + permanent Wc 6144
    float* smF = (float*)smB;      // C-dump alias (over ring bufs only)
    const int SIN_ = 2112, SHN_ = 3200, WCP = 18432;

    // ---- staging descriptors: 3 x 16B segs per thread per K64 granule ----
    // granule buf = 2 chunks x (96 rows x 32 shorts); row = pl*48 + n,
    // n = gate*16 + col16. seg = tid + i*256 in [0,768).
    const char* wB[3]; const char* cB[3]; int lo_[3];
    #pragma unroll
    for (int i = 0; i < 3; ++i) {
        int seg = tid + (i << 8);
        int cg = seg / 384, s = seg % 384;
        int row = s >> 2, ss = s & 3;
        int pln = row / 48, n = row % 48;
        int grow = (n >> 4) * HID_ + j0 + (n & 15);
        wB[i] = (const char*)(pln ? whh_lo : whh_hi)
              + (size_t)grow * 2048u + (size_t)(ss * 16 + cg * 64);
        cB[i] = (const char*)(pln ? wc_lo : wc_hi)
              + (size_t)grow * 128u + (size_t)(ss * 16 + cg * 64);
        lo_[i] = cg * 3072 + row * 32 + ((ss * 8) ^ (((row >> 1) & 3) << 3));
    }
    const int foff = l15 * 32 + ((quad * 8) ^ (((l15 >> 1) & 3) << 3));   // swz
    const size_t aoff = (size_t)((b0 + mh * 16 + l15) * 64 + quad * 16);
    const char* aAh = (const char*)hxA_hi + aoff;
    const char* aAl = (const char*)hxA_lo + aoff;
    const char* aBh = (const char*)hxB_hi + aoff;
    const char* aBl = (const char*)hxB_lo + aoff;
    const float* xrow = input + (size_t)(b0 + mh * 16 + l15) * (T_ * 64)
                              + kh * 32 + quad * 8;

    // ---- gate-phase statics: thread owns (b = b0+gb, j = j0+gj2, +1) -----
    const int gb = tid >> 3, gj2 = (tid & 7) << 1;
    float hreg[2], br[2], bz[2], bni[2], bnh[2];
    #pragma unroll
    for (int i = 0; i < 2; ++i) {
        int j = j0 + gj2 + i;
        hreg[i] = hn[(size_t)(b0 + gb) * HID_ + j];
        br[i]  = bc[j] + b_hh[j];
        bz[i]  = bc[1024 + j] + b_hh[1024 + j];
        bni[i] = bc[2048 + j];
        bnh[i] = b_hh[2048 + j];
    }
    const int j2 = j0 + gj2;
    const size_t hoff = (size_t)(j2 >> 5) * 16384 + (size_t)(b0 + gb) * 64
                      + (size_t)((j2 >> 3) & 3) * 16 + (size_t)(j2 & 7) * 2;
    char* sAh = (char*)hxA_hi + hoff; char* sAl = (char*)hxA_lo + hoff;
    char* sBh = (char*)hxB_hi + hoff; char* sBl = (char*)hxB_lo + hoff;
    const int g33 = gb * 33, g17 = gb * 17;

    int* flags = bar + bt * 128;   // 64 per-producer flags, 256B (coalesced)

    short8 bp[2][3];   // weight payload for a K64 granule, set = granule&1
    short8 ab[3][2];   // A-frag banks [granule%3][hi/lo]
    f32x4 acc[3];      // r, z, n(gh)
    f32x4 acci;        // n(gi)

    // ---- one-time: stage Wc into the permanent LDS region ----
    {
        short8 cp[3];
        #pragma unroll
        for (int j = 0; j < 3; ++j)
            gl16(cp[j], cB[j]);
        WAITV0();
        #pragma unroll
        for (int j = 0; j < 3; ++j)
            *(short8*)(smB + WCP + lo_[j]) = cp[j];
        ABAR();
    }

#define ISSUE_A(BK, C)                                                       \
  { gl16c(ab[BK][0], rh + (size_t)(C) * 16384);                              \
    gl16c(ab[BK][1], rl + (size_t)(C) * 16384); }
#define GH_CHUNK(RB, AH, AL)                                                 \
  { _Pragma("unroll")                                                        \
    for (int nt = 0; nt < 3; ++nt) {                                         \
        short8 bh_ = *(const short8*)(smB + (RB) + nt * 512 + foff);         \
        short8 bl_ = *(const short8*)(smB + (RB) + 1536 + nt * 512 + foff);  \
        f32x4 v_ = mfma_(AH, bh_, acc[nt]);                                  \
        v_ = mfma_(AH, bl_, v_);                                             \
        v_ = mfma_(AL, bh_, v_);                                             \
        acc[nt] = v_; } }

    #pragma unroll 1
    for (int t = 0; t < 256; ++t) {
        const char* rh = (t & 1) ? aBh : aAh;   // read planes (h in)
        const char* rl = (t & 1) ? aBl : aAl;
        char* wh = (t & 1) ? sAh : sBh;         // write planes (h out)
        char* wl = (t & 1) ? sAl : sBl;

        // ---- x_t load + split (plain cached loads; compiler waits) ----
        float xv[8];
        *(float4*)&xv[0] = *(const float4*)(xrow + (size_t)t * 64);
        *(float4*)&xv[4] = *(const float4*)(xrow + (size_t)t * 64 + 4);
        short8 xa_hi, xa_lo;
        #pragma unroll
        for (int i = 0; i < 8; ++i) {
            unsigned short h = bf16hi(xv[i]);
            ((short*)&xa_hi)[i] = (short)h;
            ((short*)&xa_lo)[i] = (short)bf16hi(xv[i] - bf2f(h));
        }
        WAITV0();
        // issue w_hh granules 0 and 1 pre-spin (weights step-invariant)
        #pragma unroll
        for (int j = 0; j < 3; ++j)
            gl16(bp[0][j], wB[j]);
        #pragma unroll
        for (int j = 0; j < 3; ++j)
            gl16(bp[1][j], wB[j] + 128);
        // ---- gi compute from the PERMANENT Wc region (chunk = kh) ----
        {
            const int rb = WCP + kh * 3072;
            #pragma unroll
            for (int nt = 0; nt < 3; ++nt) {
                short8 bh_ = *(const short8*)(smB + rb + nt * 512 + foff);
                short8 bl_ = *(const short8*)(smB + rb + 1536 + nt * 512 + foff);
                f32x4 z = {0.f, 0.f, 0.f, 0.f};
                f32x4 v = mfma_(xa_hi, bh_, z);
                v = mfma_(xa_hi, bl_, v);
                v = mfma_(xa_lo, bh_, v);
                if (nt < 2) { acc[nt] = v; }
                else { acci = v; acc[2] = z; }
            }
        }
        // ---- wait for h(t): parallel poll of the 64 producer flags ----
        if (t > 0 && wid == 0) {
            int fl = __hip_atomic_load(flags + lane, __ATOMIC_RELAXED,
                                       __HIP_MEMORY_SCOPE_SYSTEM);
            while (__any(fl < t)) {
                __builtin_amdgcn_s_sleep(1);
                fl = __hip_atomic_load(flags + lane, __ATOMIC_RELAXED,
                                       __HIP_MEMORY_SCOPE_SYSTEM);
            }
        }
        ABAR();
        // ---- prologue: A(granule 0), write W0 -> buf0, A(granule 1) ----
        ISSUE_A(0, kh);
        WAITV5();                  // queue {W0(3),W1(3),A0(2)} -> forces W0
        #pragma unroll
        for (int j = 0; j < 3; ++j)
            *(short8*)(smB + lo_[j]) = bp[0][j];
        ISSUE_A(1, 2 + kh);
        ABAR();
        // ---- gh pipeline: 16 K64 granules, ring-3, 1 barrier each ----
        #pragma unroll
        for (int G = 0; G < 16; ++G) {
            if (G <= 13) {
                #pragma unroll
                for (int j = 0; j < 3; ++j)
                    gl16(bp[G & 1][j], wB[j] + (size_t)(G + 2) * 128);
                ISSUE_A((G + 2) % 3, 2 * (G + 2) + kh);
                WAITV7_T(ab[G % 3][0], ab[G % 3][1]);
            } else if (G == 14) {
                WAITV2_T(ab[2][0], ab[2][1]);
            } else {
                WAITV0_T(ab[0][0], ab[0][1]);
            }
            if (G <= 14) {
                #pragma unroll
                for (int j = 0; j < 3; ++j)
                    *(short8*)(smB + ((G + 1) % 3) * 6144 + lo_[j])
                        = bp[(G + 1) & 1][j];
                ABAR();
            }
            GH_CHUNK((G % 3) * 6144 + kh * 3072, ab[G % 3][0], ab[G % 3][1]);
        }
        __syncthreads();
        // ---- dump C fragments (aliased over ring bufs) ----
        {
            const int row = mh * 16 + quad * 4;
            #pragma unroll
            for (int nt = 0; nt < 2; ++nt)
                #pragma unroll
                for (int r = 0; r < 4; ++r)
                    smF[kh * 1056 + (row + r) * 33 + nt * 16 + l15] = acc[nt][r];
            #pragma unroll
            for (int r = 0; r < 4; ++r) {
                smF[SHN_ + kh * 544 + (row + r) * 17 + l15] = acc[2][r];
                smF[SIN_ + kh * 544 + (row + r) * 17 + l15] = acci[r];
            }
        }
        __syncthreads();
        // ---- gate phase: thread owns (gb, gj2, +1); hprev in registers ----
        unsigned short ph2[2], pl2[2];
        #pragma unroll
        for (int i = 0; i < 2; ++i) {
            int cl = gj2 + i;
            float rp = smF[g33 + cl] + smF[1056 + g33 + cl] + br[i];
            float zp = smF[g33 + 16 + cl] + smF[1056 + g33 + 16 + cl] + bz[i];
            float ip = smF[SIN_ + g17 + cl] + smF[SIN_ + 544 + g17 + cl] + bni[i];
            float hp = smF[SHN_ + g17 + cl] + smF[SHN_ + 544 + g17 + cl] + bnh[i];
            float rr = sigmoidf_(rp);
            float zz = sigmoidf_(zp);
            float nn = tanhf_(ip + rr * hp);
            float hv = (1.0f - zz) * nn + zz * hreg[i];
            hreg[i] = hv;
            unsigned short hh = bf16hi(hv);
            ph2[i] = hh;
            pl2[i] = bf16hi(hv - bf2f(hh));
        }
        unsigned pk_hi = (unsigned)ph2[0] | ((unsigned)ph2[1] << 16);
        unsigned pk_lo = (unsigned)pl2[0] | ((unsigned)pl2[1] << 16);
        gs4c(wh, pk_hi);
        gs4c(wl, pk_lo);
        if (t == 255) {
            #pragma unroll
            for (int i = 0; i < 2; ++i)
                hn_out[(size_t)(b0 + gb) * HID_ + j0 + gj2 + i] = hreg[i];
        }
        WAITV0();           // h-plane stores at coherence point
        __syncthreads();    // whole block done
        if (t < 255 && tid == 0)
            __hip_atomic_store(flags + ct, t + 1, __ATOMIC_RELAXED,
                               __HIP_MEMORY_SCOPE_SYSTEM);
    }
#undef GH_CHUNK
#undef ISSUE_A
}

// ---------------- fc3: out3 = relu(relu(h) @ fc3_wT + fc3_b) --------------
__global__ __launch_bounds__(256) void k_fc3(
    const float* __restrict__ h, const float* __restrict__ fc3_w,
    const float* __restrict__ fc3_b, float* __restrict__ out3)
{
    const int bt = blockIdx.x >> 3;
    const int dt = blockIdx.x & 7;
    const int b0 = bt << 6;
    const int d0 = dt << 6;
    const int tid = threadIdx.x;
    const int tx = tid & 15, ty = tid >> 4;

    __shared__ float sh_h[64][36];
    __shared__ float sh_w[64][36];

    float acc[4][4] = {};
    const int lr = tid >> 3;
    const int lc = (tid & 7) << 2;

    for (int kk = 0; kk < HID_; kk += 32) {
        #pragma unroll
        for (int p = 0; p < 2; ++p) {
            int row = lr + (p << 5);
            float4 v = *(const float4*)(h + (size_t)(b0 + row) * HID_ + kk + lc);
            v.x = fmaxf(v.x, 0.f); v.y = fmaxf(v.y, 0.f);
            v.z = fmaxf(v.z, 0.f); v.w = fmaxf(v.w, 0.f);
            *(float4*)&sh_h[row][lc] = v;
            *(float4*)&sh_w[row][lc] =
                *(const float4*)(fc3_w + (size_t)(d0 + row) * HID_ + kk + lc);
        }
        __syncthreads();
        #pragma unroll
        for (int k = 0; k < 32; ++k) {
            float hv[4], wv[4];
            #pragma unroll
            for (int i = 0; i < 4; ++i) hv[i] = sh_h[ty + (i << 4)][k];
            #pragma unroll
            for (int q = 0; q < 4; ++q) wv[q] = sh_w[tx + (q << 4)][k];
            #pragma unroll
            for (int i = 0; i < 4; ++i)
                #pragma unroll
                for (int q = 0; q < 4; ++q)
                    acc[i][q] += hv[i] * wv[q];
        }
        __syncthreads();
    }
    #pragma unroll
    for (int i = 0; i < 4; ++i) {
        int b = b0 + ty + (i << 4);
        #pragma unroll
        for (int q = 0; q < 4; ++q) {
            int d = d0 + tx + (q << 4);
            out3[(size_t)b * D2 + d] = fmaxf(acc[i][q] + fc3_b[d], 0.f);
        }
    }
}

// ---------------- heads: params[b,o] = out3[b,:]·heads_w[cid[b],o,:]+b ----
__global__ __launch_bounds__(256) void k_heads(
    const float* __restrict__ out3, const int* __restrict__ cult,
    const float* __restrict__ hw, const float* __restrict__ hb,
    float* __restrict__ params)
{
    int b = blockIdx.x;
    int o = threadIdx.x >> 4;
    int l = threadIdx.x & 15;
    int cid = cult[b];
    const float* w = hw + ((size_t)cid * 16 + o) * D2;
    const float* x = out3 + (size_t)b * D2;
    float acc = 0.f;
    #pragma unroll
    for (int m = 0; m < 8; ++m) {
        int d4 = (l + (m << 4)) << 2;
        float4 xv = *(const float4*)(x + d4);
        float4 wv = *(const float4*)(w + d4);
        acc += xv.x * wv.x + xv.y * wv.y + xv.z * wv.z + xv.w * wv.w;
    }
    #pragma unroll
    for (int s = 1; s < 16; s <<= 1)
        acc += __shfl_xor(acc, s, 16);
    if (l == 0)
        params[(size_t)b * 16 + o] = acc + hb[(size_t)cid * 16 + o];
}

extern "C" void kernel_launch(void* const* d_in, const int* in_sizes, int n_in,
                              void* d_out, int out_size, void* d_ws, size_t ws_size,
                              hipStream_t stream)
{
    const float* input = (const float*)d_in[0];
    const float* hn    = (const float*)d_in[1];
    const int*   cult  = (const int*)d_in[2];
    const float* fc1_w = (const float*)d_in[3];
    const float* fc1_b = (const float*)d_in[4];
    const float* fc2_w = (const float*)d_in[5];
    const float* fc2_b = (const float*)d_in[6];
    const float* w_ih  = (const float*)d_in[7];
    const float* w_hh  = (const float*)d_in[8];
    const float* b_ih  = (const float*)d_in[9];
    const float* b_hh  = (const float*)d_in[10];
    const float* fc3_w = (const float*)d_in[11];
    const float* fc3_b = (const float*)d_in[12];
    const float* hw    = (const float*)d_in[13];
    const float* hb    = (const float*)d_in[14];
    float* out = (float*)d_out;
    float* hn_out = out + 4096;          // params 256*16, then hn 256*1024

    char* ws = (char*)d_ws;
    int*   bar    = (int*)ws;                                   // 4 KB
    float* W2     = (float*)(ws + 4096);                        // 256 KB
    float* b2     = (float*)(ws + 266240);
    float* bc     = (float*)(ws + 270336);
    unsigned short* whh_hi = (unsigned short*)(ws + 282624);    // 6 MB
    unsigned short* whh_lo = (unsigned short*)(ws + 282624 + 6291456);
    unsigned short* wc_hi  = (unsigned short*)(ws + 12865536);
    unsigned short* wc_lo  = (unsigned short*)(ws + 13258752);
    unsigned short* hxA_hi = (unsigned short*)(ws + 13651968);
    unsigned short* hxA_lo = (unsigned short*)(ws + 14176256);
    unsigned short* hxB_hi = (unsigned short*)(ws + 14700544);
    unsigned short* hxB_lo = (unsigned short*)(ws + 15224832);
    float* out3   = (float*)(ws + 15749120);                    // 512 KB

    hipMemsetAsync(bar, 0, 4096, stream);
    k_w2<<<256, 256, 0, stream>>>(fc2_w, fc1_w, fc1_b, fc2_b, W2, b2);
    k_wc<<<768, 256, 0, stream>>>(w_ih, W2, b2, b_ih, wc_hi, wc_lo, bc);
    k_splitw<<<3072, 256, 0, stream>>>(w_hh, whh_hi, whh_lo);
    k_split_h0<<<128, 256, 0, stream>>>(hn, hxA_hi, hxA_lo);
    k_gru<<<512, 256, 0, stream>>>(input, hn, b_hh, bc,
                                   whh_hi, whh_lo, wc_hi, wc_lo,
                                   hxA_hi, hxA_lo, hxB_hi, hxB_lo,
                                   hn_out, bar);
    k_fc3<<<32, 256, 0, stream>>>(hn_out, fc3_w, fc3_b, out3);
    k_heads<<<256, 256, 0, stream>>>(out3, cult, hw, hb, out);
}